// Round 1
// baseline (766.690 us; speedup 1.0000x reference)
//
#include <hip/hip_runtime.h>
#include <hip/hip_bf16.h>

using u16 = unsigned short;
using u32 = unsigned int;

#define NN 100000
#define NE 1000000

typedef __attribute__((ext_vector_type(8))) short bfrag;
typedef __attribute__((ext_vector_type(4))) float ffrag;

#define BF16ONE2 0x3F803F80u

__device__ __forceinline__ float bf2f(u16 u) { return __uint_as_float(((u32)u) << 16); }
__device__ __forceinline__ u16 f2bf(float f) {
  u32 x = __float_as_uint(f);
  return (u16)((x + 0x7fffu + ((x >> 16) & 1u)) >> 16);
}
__device__ __forceinline__ float rdv(const void* p, long i, int f) {
  return f ? bf2f(((const u16*)p)[i]) : ((const float*)p)[i];
}
__device__ __forceinline__ void acc8(float* a, uint4 v, float w) {
  a[0] = fmaf(w, __uint_as_float(v.x << 16), a[0]);
  a[1] = fmaf(w, __uint_as_float(v.x & 0xffff0000u), a[1]);
  a[2] = fmaf(w, __uint_as_float(v.y << 16), a[2]);
  a[3] = fmaf(w, __uint_as_float(v.y & 0xffff0000u), a[3]);
  a[4] = fmaf(w, __uint_as_float(v.z << 16), a[4]);
  a[5] = fmaf(w, __uint_as_float(v.z & 0xffff0000u), a[5]);
  a[6] = fmaf(w, __uint_as_float(v.w << 16), a[6]);
  a[7] = fmaf(w, __uint_as_float(v.w & 0xffff0000u), a[7]);
}

// actual XCD id of the executing wave (learn_hip m09: HW_REG_XCC_ID returns 0..7)
__device__ __forceinline__ int xccid() {
  u32 x;
  asm("s_getreg_b32 %0, hwreg(HW_REG_XCC_ID, 0, 32)" : "=s"(x));
  return (int)(x & 7);
}

// wq (u16) element offsets
#define OWXT 0
#define OWPRE 16384
#define OWD1 32768
#define OW11 49152
#define OV21 65536
#define OWD2 81920
#define OW12 98304
#define OV22 114688
#define OWPOST 131072
#define OWET 147456

#define ASTRIDE 136
#define ESTRIDE 132

struct PrepArgs { const void* in[16]; };

__global__ void k_prep(PrepArgs a, const u32* __restrict__ gp, u16* __restrict__ wq,
                       float* __restrict__ wf) {
  int t = blockIdx.x * 256 + threadIdx.x;
  int f = (gp[0] == BF16ONE2) ? 1 : 0;
  if (t < 16384) {
    int o = t >> 7, k = t & 127;
    int ko = k * 128 + o;
    int ok = o * 128 + k;
    wq[OWXT + ok] = f2bf(rdv(a.in[0], ko, f));
    wq[OWPRE + ok] = f2bf(rdv(a.in[2], ko, f));
    float c0 = rdv(a.in[6], ko, f);
    float c1 = rdv(a.in[6], 16384 + ko, f);
    float c2 = rdv(a.in[6], 32768 + ko, f);
    wq[OWD1 + ok] = f2bf(c0 - c2);
    wq[OW11 + ok] = f2bf(c1);
    wq[OV21 + ok] = f2bf(2.f * c2);
    float d0 = rdv(a.in[8], ko, f);
    float d1 = rdv(a.in[8], 16384 + ko, f);
    float d2 = rdv(a.in[8], 32768 + ko, f);
    wq[OWD2 + ok] = f2bf(d0 - d2);
    wq[OW12 + ok] = f2bf(d1);
    wq[OV22 + ok] = f2bf(2.f * d2);
    wq[OWPOST + ok] = f2bf(rdv(a.in[10], ko, f));
  }
  if (t < 4096) {
    int o = t >> 5, k = t & 31;
    wq[OWET + o * 32 + k] = (k < 16) ? f2bf(rdv(a.in[0], (long)(128 + k) * 128 + o, f)) : (u16)0;
  }
  if (t < 1281) {
    int s = t >> 7, j = t & 127;
    const int map[11] = {1, 3, 4, 5, 7, 9, 11, 12, 13, 14, 15};
    wf[t] = rdv(a.in[map[s]], j, f);
  }
}

// ---------------- histogram: XCD-privatized, TCC-local (workgroup-scope) atomics ----------------
__global__ void k_hist(const int* __restrict__ ei, int* cntx, int* degx) {
  int e = blockIdx.x * 256 + threadIdx.x;
  if (e >= NE) return;
  int x = xccid();
  __hip_atomic_fetch_add(&degx[x * NN + ei[e]], 1, __ATOMIC_RELAXED, __HIP_MEMORY_SCOPE_WORKGROUP);
  __hip_atomic_fetch_add(&cntx[x * NN + ei[NE + e]], 1, __ATOMIC_RELAXED, __HIP_MEMORY_SCOPE_WORKGROUP);
}

// ---------------- exclusive scan (sums the 8 per-XCD copies on read) ----------------
__global__ void k_scan1(const int* __restrict__ cntx, int* off, int* bsum) {
  __shared__ int s[1024];
  int t = threadIdx.x;
  int g = blockIdx.x * 1024 + t;
  int v = 0;
  if (g < NN) {
#pragma unroll
    for (int x = 0; x < 8; x++) v += cntx[x * NN + g];
  }
  s[t] = v;
  __syncthreads();
  for (int st = 1; st < 1024; st <<= 1) {
    int x = (t >= st) ? s[t - st] : 0;
    __syncthreads();
    s[t] += x;
    __syncthreads();
  }
  if (g < NN) off[g] = s[t] - v;
  if (t == 1023) bsum[blockIdx.x] = s[t];
}

__global__ void k_scan23(int* off, const int* __restrict__ bsum,
                         const int* __restrict__ degx, float* __restrict__ dis, int nb) {
  __shared__ int s[128];
  int t = threadIdx.x;
  int v = 0;
  if (t < 128) {
    v = (t < nb) ? bsum[t] : 0;
    s[t] = v;
  }
  __syncthreads();
  for (int st = 1; st < 128; st <<= 1) {
    int x = (t >= st && t < 128) ? s[t - st] : 0;
    __syncthreads();
    if (t < 128) s[t] += x;
    __syncthreads();
  }
  if (t < 128) s[t] -= v;
  __syncthreads();
  int pre = s[blockIdx.x];
  int g = blockIdx.x * 1024 + t;
  if (g < NN) {
    off[g] += pre;
    int d = 0;
#pragma unroll
    for (int x = 0; x < 8; x++) d += degx[x * NN + g];
    dis[g] = d > 0 ? rsqrtf((float)d) : 0.f;
  }
  if (g == 0) off[NN] = NE;
}

// ---------------- per-(XCD,col) cursor bases: offx[x][c] = off[c] + sum_{y<x} cntx[y][c] ----------------
__global__ void k_offx(const int* __restrict__ off, const int* __restrict__ cntx,
                       int* __restrict__ offx) {
  int c = blockIdx.x * 256 + threadIdx.x;
  if (c >= NN) return;
  int o = off[c];
#pragma unroll
  for (int x = 0; x < 8; x++) {
    offx[x * NN + c] = o;
    o += cntx[x * NN + c];
  }
}

// ---------------- CSR placement (TCC-local fetch-add on private cursor) ----------------
__global__ void k_place(const int* __restrict__ ei, int* offx, int* crow, int* ceid) {
  int e = blockIdx.x * 256 + threadIdx.x;
  if (e >= NE) return;
  int x = xccid();
  int r = ei[e], c = ei[NE + e];
  int p = __hip_atomic_fetch_add(&offx[x * NN + c], 1, __ATOMIC_RELAXED,
                                 __HIP_MEMORY_SCOPE_WORKGROUP);
  crow[p] = r;
  ceid[p] = e;
}

// ------------- standalone SpMM (weighted): dst = L(src) -------------
__global__ __launch_bounds__(256) void k_spmm(const u16* __restrict__ src,
                                              u16* __restrict__ dst,
                                              const int* __restrict__ off,
                                              const int* __restrict__ crow,
                                              const float* __restrict__ cnorm) {
  int t = threadIdx.x;
  int node = blockIdx.x * 8 + (t >> 5);
  if (node >= NN) return;
  int l = t & 31;
  int half = l >> 4;
  int c = (l & 15) * 8;
  int p0 = off[node], p1 = off[node + 1];
  float a[8];
#pragma unroll
  for (int j = 0; j < 8; j++) a[j] = 0.f;
  const u16* sp = src + c;
  int p = p0 + half;
  for (; p + 6 < p1; p += 8) {
    int r0 = crow[p], r1 = crow[p + 2], r2 = crow[p + 4], r3 = crow[p + 6];
    float w0 = cnorm[p], w1 = cnorm[p + 2], w2 = cnorm[p + 4], w3 = cnorm[p + 6];
    uint4 v0 = *(const uint4*)(sp + (long)r0 * 128);
    uint4 v1 = *(const uint4*)(sp + (long)r1 * 128);
    uint4 v2 = *(const uint4*)(sp + (long)r2 * 128);
    uint4 v3 = *(const uint4*)(sp + (long)r3 * 128);
    acc8(a, v0, w0);
    acc8(a, v1, w1);
    acc8(a, v2, w2);
    acc8(a, v3, w3);
  }
  for (; p < p1; p += 2) acc8(a, *(const uint4*)(sp + (long)crow[p] * 128), cnorm[p]);
#pragma unroll
  for (int j = 0; j < 8; j++) a[j] += __shfl_xor(a[j], 16);
  if (half) return;
  uint4 o;
  o.x = (u32)f2bf(a[0]) | ((u32)f2bf(a[1]) << 16);
  o.y = (u32)f2bf(a[2]) | ((u32)f2bf(a[3]) << 16);
  o.z = (u32)f2bf(a[4]) | ((u32)f2bf(a[5]) << 16);
  o.w = (u32)f2bf(a[6]) | ((u32)f2bf(a[7]) << 16);
  *(uint4*)(dst + (long)node * 128 + c) = o;
}

// ------------- gather L(src) (or segsum) for 64 rows into LDS (ASTRIDE layout) -------------
template <int WEIGHTED>
__device__ __forceinline__ void gather_lds(u16* sA, const u16* __restrict__ src,
                                           const int* __restrict__ off,
                                           const int* __restrict__ crow,
                                           const float* __restrict__ cnorm, int r0) {
  int tid = threadIdx.x;
  int grp = tid >> 4;      // 16 groups of 16 lanes
  int c = (tid & 15) * 8;  // 8 cols per lane
  const u16* sp = src + c;
#pragma unroll
  for (int i = 0; i < 4; i++) {
    int nl = grp * 4 + i;
    int node = r0 + nl;
    float a[8];
#pragma unroll
    for (int j = 0; j < 8; j++) a[j] = 0.f;
    if (node < NN) {
      int p0 = off[node], p1 = off[node + 1];
      int p = p0;
      for (; p + 4 <= p1; p += 4) {
        int r0i = crow[p], r1i = crow[p + 1], r2i = crow[p + 2], r3i = crow[p + 3];
        float w0 = WEIGHTED ? cnorm[p] : 1.f;
        float w1 = WEIGHTED ? cnorm[p + 1] : 1.f;
        float w2 = WEIGHTED ? cnorm[p + 2] : 1.f;
        float w3 = WEIGHTED ? cnorm[p + 3] : 1.f;
        uint4 v0 = *(const uint4*)(sp + (long)r0i * 128);
        uint4 v1 = *(const uint4*)(sp + (long)r1i * 128);
        uint4 v2 = *(const uint4*)(sp + (long)r2i * 128);
        uint4 v3 = *(const uint4*)(sp + (long)r3i * 128);
        acc8(a, v0, w0);
        acc8(a, v1, w1);
        acc8(a, v2, w2);
        acc8(a, v3, w3);
      }
      for (; p < p1; p++)
        acc8(a, *(const uint4*)(sp + (long)crow[p] * 128), WEIGHTED ? cnorm[p] : 1.f);
    }
    uint4 o;
    o.x = (u32)f2bf(a[0]) | ((u32)f2bf(a[1]) << 16);
    o.y = (u32)f2bf(a[2]) | ((u32)f2bf(a[3]) << 16);
    o.z = (u32)f2bf(a[4]) | ((u32)f2bf(a[5]) << 16);
    o.w = (u32)f2bf(a[6]) | ((u32)f2bf(a[7]) << 16);
    *(uint4*)(sA + nl * ASTRIDE + c) = o;
  }
}

// ------------- edge_attr segment-sum ([N,16]) + cnorm precompute -------------
__global__ __launch_bounds__(256) void k_asum(const void* __restrict__ eattr,
                                              const u32* __restrict__ gp,
                                              u16* __restrict__ asum,
                                              const int* __restrict__ off,
                                              const int* __restrict__ ceid,
                                              const int* __restrict__ crow,
                                              const float* __restrict__ dis,
                                              float* __restrict__ cnorm) {
  int t = blockIdx.x * 256 + threadIdx.x;
  int node = t >> 4;
  if (node >= NN) return;
  int j = t & 15;
  int p0 = off[node], p1 = off[node + 1];
  float ndis = -dis[node];
  for (int p = p0 + j; p < p1; p += 16) cnorm[p] = ndis * dis[crow[p]];
  float a = 0.f;
  if (gp[0] == BF16ONE2) {
    const u16* e16 = (const u16*)eattr;
    int p = p0;
    for (; p + 4 <= p1; p += 4) {
      float v0 = bf2f(e16[(long)ceid[p] * 16 + j]);
      float v1 = bf2f(e16[(long)ceid[p + 1] * 16 + j]);
      float v2 = bf2f(e16[(long)ceid[p + 2] * 16 + j]);
      float v3 = bf2f(e16[(long)ceid[p + 3] * 16 + j]);
      a += v0 + v1 + v2 + v3;
    }
    for (; p < p1; p++) a += bf2f(e16[(long)ceid[p] * 16 + j]);
  } else {
    const float* e32 = (const float*)eattr;
    int p = p0;
    for (; p + 4 <= p1; p += 4) {
      float v0 = e32[(long)ceid[p] * 16 + j];
      float v1 = e32[(long)ceid[p + 1] * 16 + j];
      float v2 = e32[(long)ceid[p + 2] * 16 + j];
      float v3 = e32[(long)ceid[p + 3] * 16 + j];
      a += v0 + v1 + v2 + v3;
    }
    for (; p < p1; p++) a += e32[(long)ceid[p] * 16 + j];
  }
  asum[(long)node * 16 + j] = f2bf(a);
}

// ------------- plain MFMA GEMM (ROWS=128): out = A0@W0T^T + bias (+partials) -------------
struct MArgs {
  const void* A0; const u16* W0T; int a0raw;
  const float* bias;
  u16* out;
  const u32* gp;
  float* part;
};

__global__ __launch_bounds__(256) void k_mgemm(MArgs m) {
  constexpr int ROWS = 128, RT = 8, TPR = 2, SEGW = 64;
  __shared__ __align__(16) u16 sA[ROWS * ASTRIDE];
  int tid = threadIdx.x;
  int wv = tid >> 6, lane = tid & 63;
  int col16 = lane & 15, quad = lane >> 4;
  int r0 = blockIdx.x * ROWS;

  ffrag acc[RT * 2];
#pragma unroll
  for (int i = 0; i < RT * 2; i++)
#pragma unroll
    for (int g = 0; g < 4; g++) acc[i][g] = 0.f;

  {
    int row = tid / TPR, seg = tid % TPR;
    int ra = r0 + row;
    if (ra >= NN) ra = NN - 1;
    bool f32a = m.a0raw && (m.gp[0] != BF16ONE2);
    if (f32a) {
      const float* gs = (const float*)m.A0 + (long)ra * 128 + seg * SEGW;
      u32* lp = (u32*)(sA + row * ASTRIDE + seg * SEGW);
#pragma unroll
      for (int e = 0; e < SEGW / 8; e++) {
        float4 v0 = *(const float4*)(gs + e * 8);
        float4 v1 = *(const float4*)(gs + e * 8 + 4);
        lp[e * 4 + 0] = (u32)f2bf(v0.x) | ((u32)f2bf(v0.y) << 16);
        lp[e * 4 + 1] = (u32)f2bf(v0.z) | ((u32)f2bf(v0.w) << 16);
        lp[e * 4 + 2] = (u32)f2bf(v1.x) | ((u32)f2bf(v1.y) << 16);
        lp[e * 4 + 3] = (u32)f2bf(v1.z) | ((u32)f2bf(v1.w) << 16);
      }
    } else {
      const u16* gs = (const u16*)m.A0 + (long)ra * 128 + seg * SEGW;
      uint4* lp = (uint4*)(sA + row * ASTRIDE + seg * SEGW);
#pragma unroll
      for (int e = 0; e < SEGW / 8; e++) lp[e] = *(const uint4*)(gs + e * 8);
    }
  }
  bfrag b0[2][4];
#pragma unroll
  for (int c = 0; c < 2; c++)
#pragma unroll
    for (int kb = 0; kb < 4; kb++)
      b0[c][kb] = *(const bfrag*)(m.W0T + (long)(wv * 32 + c * 16 + col16) * 128 + kb * 32 + quad * 8);
  __syncthreads();
#pragma unroll
  for (int kb = 0; kb < 4; kb++)
#pragma unroll
    for (int rt = 0; rt < RT; rt++) {
      bfrag af = *(const bfrag*)(sA + (rt * 16 + col16) * ASTRIDE + kb * 32 + quad * 8);
      acc[rt * 2 + 0] = __builtin_amdgcn_mfma_f32_16x16x32_bf16(af, b0[0][kb], acc[rt * 2 + 0], 0, 0, 0);
      acc[rt * 2 + 1] = __builtin_amdgcn_mfma_f32_16x16x32_bf16(af, b0[1][kb], acc[rt * 2 + 1], 0, 0, 0);
    }
  __syncthreads();
#pragma unroll
  for (int rt = 0; rt < RT; rt++)
#pragma unroll
    for (int c = 0; c < 2; c++) {
      int col = wv * 32 + c * 16 + col16;
      float bj = m.bias ? m.bias[col] : 0.f;
#pragma unroll
      for (int g = 0; g < 4; g++)
        sA[(rt * 16 + quad * 4 + g) * ESTRIDE + col] = f2bf(acc[rt * 2 + c][g] + bj);
    }
  __syncthreads();
  {
    int rr = tid / TPR, d = tid % TPR;
    int rowg = r0 + rr;
    if (rowg < NN) {
      const u16* sp2 = sA + rr * ESTRIDE + d * 64;
      uint4* o = (uint4*)(m.out + (long)rowg * 128 + d * 64);
#pragma unroll
      for (int e = 0; e < 8; e++) {
        const uint2* s2 = (const uint2*)(sp2 + e * 8);
        uint2 lo = s2[0], hi = s2[1];
        o[e] = make_uint4(lo.x, lo.y, hi.x, hi.y);
      }
    }
  }
  if (m.part) {
    __shared__ float ps[256], pq[256];
    int col = tid & 127, hf = tid >> 7;
    float s = 0.f, q = 0.f;
#pragma unroll
    for (int r = 0; r < 64; r++) {
      int rr = hf * 64 + r;
      if (r0 + rr < NN) {
        float v = bf2f(sA[rr * ESTRIDE + col]);
        s += v;
        q += v * v;
      }
    }
    ps[tid] = s;
    pq[tid] = q;
    __syncthreads();
    if (tid < 128) {
      m.part[(long)blockIdx.x * 256 + tid] = ps[tid] + ps[tid + 128];
      m.part[(long)blockIdx.x * 256 + 128 + tid] = pq[tid] + pq[tid + 128];
    }
  }
}

// ------------- fused: S-gather + ET GEMM + mean + preprocess GEMM -------------
__global__ __launch_bounds__(256) void k_etpre(const u16* __restrict__ Xg,
                                               const u16* __restrict__ asum,
                                               const u16* __restrict__ Wet,
                                               const u16* __restrict__ Wpre,
                                               const float* __restrict__ b_int,
                                               const float* __restrict__ b_pre,
                                               const int* __restrict__ off,
                                               const int* __restrict__ crow,
                                               u16* __restrict__ out, float* part) {
  __shared__ __align__(16) u16 sA[64 * ASTRIDE];
  int tid = threadIdx.x;
  int wv = tid >> 6, lane = tid & 63;
  int col16 = lane & 15, quad = lane >> 4;
  int r0 = blockIdx.x * 64;

  // stage asum [64 x 16] into cols 0..15, zero 16..31
  {
    int row = tid >> 2, seg = tid & 3;
    int ra = r0 + row;
    if (ra >= NN) ra = NN - 1;
    if (seg < 2)
      *(uint4*)(sA + row * ASTRIDE + seg * 8) = *(const uint4*)(asum + (long)ra * 16 + seg * 8);
    else
      *(uint4*)(sA + row * ASTRIDE + seg * 8) = make_uint4(0, 0, 0, 0);
  }
  bfrag be[2];
#pragma unroll
  for (int c = 0; c < 2; c++)
    be[c] = *(const bfrag*)(Wet + (long)(wv * 32 + c * 16 + col16) * 32 + quad * 8);
  __syncthreads();
  ffrag accE[8];
#pragma unroll
  for (int i = 0; i < 8; i++)
#pragma unroll
    for (int g = 0; g < 4; g++) accE[i][g] = 0.f;
#pragma unroll
  for (int rt = 0; rt < 4; rt++) {
    bfrag af = *(const bfrag*)(sA + (rt * 16 + col16) * ASTRIDE + quad * 8);
    accE[rt * 2 + 0] = __builtin_amdgcn_mfma_f32_16x16x32_bf16(af, be[0], accE[rt * 2 + 0], 0, 0, 0);
    accE[rt * 2 + 1] = __builtin_amdgcn_mfma_f32_16x16x32_bf16(af, be[1], accE[rt * 2 + 1], 0, 0, 0);
  }
  __syncthreads();
  // gather S = segsum(Xg) into sA (full 128 cols)
  gather_lds<0>(sA, Xg, off, crow, nullptr, r0);
  __syncthreads();
  // h = (accE + S + cnt*b)/max(cnt,1)  -> in-place at C-layout positions
  // cnt[r] == off[r+1]-off[r] (in-degree)
#pragma unroll
  for (int rt = 0; rt < 4; rt++)
#pragma unroll
    for (int g = 0; g < 4; g++) {
      int rr = rt * 16 + quad * 4 + g;
      int r = r0 + rr;
      int cc = (r < NN) ? off[r + 1] - off[r] : 0;
      float inv = 1.f / (float)(cc > 1 ? cc : 1);
#pragma unroll
      for (int c = 0; c < 2; c++) {
        int col = wv * 32 + c * 16 + col16;
        float bj = b_int[col];
        float v = accE[rt * 2 + c][g] + bf2f(sA[rr * ASTRIDE + col]);
        v = (v + (float)cc * bj) * inv;
        sA[rr * ASTRIDE + col] = f2bf(v);
      }
    }
  bfrag b1[2][4];
#pragma unroll
  for (int c = 0; c < 2; c++)
#pragma unroll
    for (int kb = 0; kb < 4; kb++)
      b1[c][kb] = *(const bfrag*)(Wpre + (long)(wv * 32 + c * 16 + col16) * 128 + kb * 32 + quad * 8);
  __syncthreads();
  ffrag a2[8];
#pragma unroll
  for (int i = 0; i < 8; i++)
#pragma unroll
    for (int g = 0; g < 4; g++) a2[i][g] = 0.f;
#pragma unroll
  for (int kb = 0; kb < 4; kb++)
#pragma unroll
    for (int rt = 0; rt < 4; rt++) {
      bfrag af = *(const bfrag*)(sA + (rt * 16 + col16) * ASTRIDE + kb * 32 + quad * 8);
      a2[rt * 2 + 0] = __builtin_amdgcn_mfma_f32_16x16x32_bf16(af, b1[0][kb], a2[rt * 2 + 0], 0, 0, 0);
      a2[rt * 2 + 1] = __builtin_amdgcn_mfma_f32_16x16x32_bf16(af, b1[1][kb], a2[rt * 2 + 1], 0, 0, 0);
    }
  __syncthreads();
#pragma unroll
  for (int rt = 0; rt < 4; rt++)
#pragma unroll
    for (int c = 0; c < 2; c++) {
      int col = wv * 32 + c * 16 + col16;
      float bj = b_pre[col];
#pragma unroll
      for (int g = 0; g < 4; g++)
        sA[(rt * 16 + quad * 4 + g) * ESTRIDE + col] = f2bf(a2[rt * 2 + c][g] + bj);
    }
  __syncthreads();
  {
    int rr = tid >> 2, d = tid & 3;
    int rowg = r0 + rr;
    if (rowg < NN) {
      const u16* sp2 = sA + rr * ESTRIDE + d * 32;
      uint4* o = (uint4*)(out + (long)rowg * 128 + d * 32);
#pragma unroll
      for (int e = 0; e < 4; e++) {
        const uint2* s2 = (const uint2*)(sp2 + e * 8);
        uint2 lo = s2[0], hi = s2[1];
        o[e] = make_uint4(lo.x, lo.y, hi.x, hi.y);
      }
    }
  }
  {
    __shared__ float ps[256], pq[256];
    int col = tid & 127, hf = tid >> 7;
    float s = 0.f, q = 0.f;
#pragma unroll
    for (int r = 0; r < 32; r++) {
      int rr = hf * 32 + r;
      if (r0 + rr < NN) {
        float v = bf2f(sA[rr * ESTRIDE + col]);
        s += v;
        q += v * v;
      }
    }
    ps[tid] = s;
    pq[tid] = q;
    __syncthreads();
    if (tid < 128) {
      part[(long)blockIdx.x * 256 + tid] = ps[tid] + ps[tid + 128];
      part[(long)blockIdx.x * 256 + 128 + tid] = pq[tid] + pq[tid + 128];
    }
  }
}

// ------------- fused cheb layer: out = relu(hb@WD + T1@W1 + L(T1)@V2 + b), in-place over hb -------------
__global__ __launch_bounds__(256) void k_cheb(const u16* __restrict__ hb,
                                              const u16* __restrict__ T1,
                                              const int* __restrict__ off,
                                              const int* __restrict__ crow,
                                              const float* __restrict__ cnorm,
                                              const u16* __restrict__ WD,
                                              const u16* __restrict__ W1,
                                              const u16* __restrict__ V2,
                                              const float* __restrict__ bias,
                                              u16* __restrict__ out) {
  __shared__ __align__(16) u16 sA[64 * ASTRIDE];
  int tid = threadIdx.x;
  int wv = tid >> 6, lane = tid & 63;
  int col16 = lane & 15, quad = lane >> 4;
  int r0 = blockIdx.x * 64;

  ffrag acc[8];
#pragma unroll
  for (int i = 0; i < 8; i++)
#pragma unroll
    for (int g = 0; g < 4; g++) acc[i][g] = 0.f;

  // phase 1: gather L(T1) -> sA ; MFMA with V2
  gather_lds<1>(sA, T1, off, crow, cnorm, r0);
  bfrag bv[2][4];
#pragma unroll
  for (int c = 0; c < 2; c++)
#pragma unroll
    for (int kb = 0; kb < 4; kb++)
      bv[c][kb] = *(const bfrag*)(V2 + (long)(wv * 32 + c * 16 + col16) * 128 + kb * 32 + quad * 8);
  __syncthreads();
#pragma unroll
  for (int kb = 0; kb < 4; kb++)
#pragma unroll
    for (int rt = 0; rt < 4; rt++) {
      bfrag af = *(const bfrag*)(sA + (rt * 16 + col16) * ASTRIDE + kb * 32 + quad * 8);
      acc[rt * 2 + 0] = __builtin_amdgcn_mfma_f32_16x16x32_bf16(af, bv[0][kb], acc[rt * 2 + 0], 0, 0, 0);
      acc[rt * 2 + 1] = __builtin_amdgcn_mfma_f32_16x16x32_bf16(af, bv[1][kb], acc[rt * 2 + 1], 0, 0, 0);
    }
  __syncthreads();

  // phase 2: stage hb own rows ; MFMA with WD
  {
    int row = tid >> 2, seg = tid & 3;
    int ra = r0 + row;
    if (ra >= NN) ra = NN - 1;
    const u16* gs = hb + (long)ra * 128 + seg * 32;
    uint4* lp = (uint4*)(sA + row * ASTRIDE + seg * 32);
#pragma unroll
    for (int e = 0; e < 4; e++) lp[e] = *(const uint4*)(gs + e * 8);
  }
#pragma unroll
  for (int c = 0; c < 2; c++)
#pragma unroll
    for (int kb = 0; kb < 4; kb++)
      bv[c][kb] = *(const bfrag*)(WD + (long)(wv * 32 + c * 16 + col16) * 128 + kb * 32 + quad * 8);
  __syncthreads();
#pragma unroll
  for (int kb = 0; kb < 4; kb++)
#pragma unroll
    for (int rt = 0; rt < 4; rt++) {
      bfrag af = *(const bfrag*)(sA + (rt * 16 + col16) * ASTRIDE + kb * 32 + quad * 8);
      acc[rt * 2 + 0] = __builtin_amdgcn_mfma_f32_16x16x32_bf16(af, bv[0][kb], acc[rt * 2 + 0], 0, 0, 0);
      acc[rt * 2 + 1] = __builtin_amdgcn_mfma_f32_16x16x32_bf16(af, bv[1][kb], acc[rt * 2 + 1], 0, 0, 0);
    }
  __syncthreads();

  // phase 3: stage T1 own rows ; MFMA with W1
  {
    int row = tid >> 2, seg = tid & 3;
    int ra = r0 + row;
    if (ra >= NN) ra = NN - 1;
    const u16* gs = T1 + (long)ra * 128 + seg * 32;
    uint4* lp = (uint4*)(sA + row * ASTRIDE + seg * 32);
#pragma unroll
    for (int e = 0; e < 4; e++) lp[e] = *(const uint4*)(gs + e * 8);
  }
#pragma unroll
  for (int c = 0; c < 2; c++)
#pragma unroll
    for (int kb = 0; kb < 4; kb++)
      bv[c][kb] = *(const bfrag*)(W1 + (long)(wv * 32 + c * 16 + col16) * 128 + kb * 32 + quad * 8);
  __syncthreads();
#pragma unroll
  for (int kb = 0; kb < 4; kb++)
#pragma unroll
    for (int rt = 0; rt < 4; rt++) {
      bfrag af = *(const bfrag*)(sA + (rt * 16 + col16) * ASTRIDE + kb * 32 + quad * 8);
      acc[rt * 2 + 0] = __builtin_amdgcn_mfma_f32_16x16x32_bf16(af, bv[0][kb], acc[rt * 2 + 0], 0, 0, 0);
      acc[rt * 2 + 1] = __builtin_amdgcn_mfma_f32_16x16x32_bf16(af, bv[1][kb], acc[rt * 2 + 1], 0, 0, 0);
    }
  __syncthreads();

  // epilogue: +bias, relu, repack, store
#pragma unroll
  for (int rt = 0; rt < 4; rt++)
#pragma unroll
    for (int c = 0; c < 2; c++) {
      int col = wv * 32 + c * 16 + col16;
      float bj = bias[col];
#pragma unroll
      for (int g = 0; g < 4; g++)
        sA[(rt * 16 + quad * 4 + g) * ESTRIDE + col] = f2bf(fmaxf(acc[rt * 2 + c][g] + bj, 0.f));
    }
  __syncthreads();
  {
    int rr = tid >> 2, d = tid & 3;
    int rowg = r0 + rr;
    if (rowg < NN) {
      const u16* sp2 = sA + rr * ESTRIDE + d * 32;
      uint4* o = (uint4*)(out + (long)rowg * 128 + d * 32);
#pragma unroll
      for (int e = 0; e < 4; e++) {
        const uint2* s2 = (const uint2*)(sp2 + e * 8);
        uint2 lo = s2[0], hi = s2[1];
        o[e] = make_uint4(lo.x, lo.y, hi.x, hi.y);
      }
    }
  }
}

// ------------- reduce partials + BN finalize fused -------------
__global__ void k_redfin(const float* __restrict__ part, const float* __restrict__ gamma,
                         const float* __restrict__ beta, float* ab, int nblk) {
  int tid = threadIdx.x;
  int col = blockIdx.x * 16 + (tid & 15);
  int ch = tid >> 4;
  float s = 0.f, q = 0.f;
  for (int b = ch; b < nblk; b += 16) {
    s += part[(long)b * 256 + col];
    q += part[(long)b * 256 + 128 + col];
  }
  __shared__ float sh[256], qh[256];
  sh[tid] = s;
  qh[tid] = q;
  __syncthreads();
  if (tid < 16) {
    float ts = 0.f, tq = 0.f;
#pragma unroll
    for (int i = 0; i < 16; i++) {
      ts += sh[i * 16 + tid];
      tq += qh[i * 16 + tid];
    }
    int j = blockIdx.x * 16 + tid;
    float m = ts * (1.f / (float)NN);
    float v = fmaxf(tq * (1.f / (float)NN) - m * m, 0.f);
    float a = gamma[j] * rsqrtf(v + 1e-5f);
    ab[j] = a;
    ab[128 + j] = beta[j] - m * a;
  }
}

__global__ void k_bnrelu(const u16* __restrict__ z, u16* __restrict__ out,
                         const float* __restrict__ ab) {
  long idx = (long)blockIdx.x * 256 + threadIdx.x;
  long t = idx * 2;
  if (t >= (long)NN * 128) return;
  int col = (int)(t & 127);
  u32 v = *(const u32*)(z + t);
  float f0 = fmaxf(__uint_as_float(v << 16) * ab[col] + ab[128 + col], 0.f);
  float f1 = fmaxf(__uint_as_float(v & 0xffff0000u) * ab[col + 1] + ab[129 + col], 0.f);
  *(u32*)(out + t) = (u32)f2bf(f0) | ((u32)f2bf(f1) << 16);
}

__global__ void k_out(const u16* __restrict__ z, const float* __restrict__ ab,
                      const float* __restrict__ wout, const float* __restrict__ bout,
                      const u32* __restrict__ gp, void* __restrict__ y) {
  int node = blockIdx.x * 4 + (threadIdx.x >> 6);
  if (node >= NN) return;
  int lane = threadIdx.x & 63;
  float s = 0.f;
#pragma unroll
  for (int c = lane; c < 128; c += 64) {
    float zz = bf2f(z[(long)node * 128 + c]);
    float h = fmaxf(ab[c] * zz + ab[128 + c], 0.f);
    s += h * wout[c];
  }
#pragma unroll
  for (int o = 32; o > 0; o >>= 1) s += __shfl_down(s, o);
  if (lane == 0) {
    float r = s + bout[0];
    if (gp[0] == BF16ONE2) ((u16*)y)[node] = f2bf(r);
    else ((float*)y)[node] = r;
  }
}

extern "C" void kernel_launch(void* const* d_in, const int* in_sizes, int n_in,
                              void* d_out, int out_size, void* d_ws, size_t ws_size,
                              hipStream_t stream) {
  const void* x = d_in[0];
  const int* ei = (const int*)d_in[1];
  const void* eattr = d_in[2];
  const u32* gp = (const u32*)d_in[7];
  (void)in_sizes; (void)n_in; (void)out_size; (void)ws_size;

  char* w = (char*)d_ws;
  size_t p = 0;
  auto alloc = [&](size_t b) { size_t r = p; p += (b + 255) & ~(size_t)255; return r; };
  size_t o_dis = alloc((size_t)NN * 4);
  size_t o_off = alloc((size_t)(NN + 1) * 4);
  size_t o_bsum = alloc(1024 * 4);
  size_t o_ab = alloc(512 * 4);
  size_t o_wq = alloc((size_t)151552 * 2);
  size_t o_wf = alloc((size_t)1281 * 4);
  size_t o_crow = alloc((size_t)NE * 4);
  size_t o_cnrm = alloc((size_t)NE * 4);
  size_t o_asum = alloc((size_t)NN * 16 * 2);
  size_t o_part = alloc((size_t)1563 * 256 * 4);
  size_t o_Bx = alloc((size_t)NN * 128 * 2);
  size_t o_Bt = alloc((size_t)NN * 128 * 2);

  float* dis = (float*)(w + o_dis);
  int* off = (int*)(w + o_off);
  int* bsum = (int*)(w + o_bsum);
  float* abA = (float*)(w + o_ab);
  float* abB = abA + 256;
  u16* wq = (u16*)(w + o_wq);
  float* wf = (float*)(w + o_wf);
  int* crow = (int*)(w + o_crow);
  float* cnrm = (float*)(w + o_cnrm);
  u16* asum = (u16*)(w + o_asum);
  float* part = (float*)(w + o_part);
  u16* Bx = (u16*)(w + o_Bx);
  u16* Bt = (u16*)(w + o_Bt);
  // transient overlays (all dead before Bx/Bt are first written by GEMM stage):
  int* cntx = (int*)Bx;              // 8 x NN in-degree copies   (dead after k_offx)
  int* degx = cntx + 8 * NN;         // 8 x NN out-degree copies  (dead after k_scan23)
  int* offx = degx + 8 * NN;         // 8 x NN cursor bases       (dead after k_place)
  int* ceid = (int*)Bt;              // edge ids in CSR order     (dead after k_asum)

  hipMemsetAsync(cntx, 0, (size_t)8 * NN * 4 * 2, stream);  // zero cntx+degx

  int gE = (NE + 255) / 256;
  int nb = (NN + 1023) / 1024;
  int gS = (NN + 7) / 8;
  int gN = (NN + 255) / 256;
  int gG1 = (NN + 127) / 128;  // 782
  int gG2 = (NN + 63) / 64;    // 1563

  {
    PrepArgs a;
    for (int i = 0; i < 16; i++) a.in[i] = d_in[3 + i];
    k_prep<<<64, 256, 0, stream>>>(a, gp, wq, wf);
  }

  k_hist<<<gE, 256, 0, stream>>>(ei, cntx, degx);
  k_scan1<<<nb, 1024, 0, stream>>>(cntx, off, bsum);
  k_scan23<<<nb, 1024, 0, stream>>>(off, bsum, degx, dis, nb);
  k_offx<<<gN, 256, 0, stream>>>(off, cntx, offx);
  k_place<<<gE, 256, 0, stream>>>(ei, offx, crow, ceid);
  k_asum<<<(NN * 16 + 255) / 256, 256, 0, stream>>>(eattr, gp, asum, off, ceid, crow, dis, cnrm);

  // ---- Xg = x @ Wx -> Bx (must materialize: gather src)
  {
    MArgs a = {};
    a.A0 = x; a.W0T = wq + OWXT; a.a0raw = 1;
    a.out = Bx; a.gp = gp;
    k_mgemm<<<gG1, 256, 0, stream>>>(a);
  }
  // ---- fused: S = segsum(Xg) (gather in-kernel), h = (S+asum@We+cnt*b)/cnt, z = h@Wpre+b -> Bt
  k_etpre<<<gG2, 256, 0, stream>>>(Bx, asum, wq + OWET, wq + OWPRE, wf + 0, wf + 128,
                                   off, crow, Bt, part);
  k_redfin<<<8, 256, 0, stream>>>(part, wf + 256, wf + 384, abA, gG2);
  // ---- hb = relu(bn(z)): Bt -> Bx
  k_bnrelu<<<(int)(((long)NN * 128 / 2 + 255) / 256), 256, 0, stream>>>(Bt, Bx, abA);

  // ---- cheb1: T1 = L(hb) -> Bt ; fused h2 = relu(hb@WD1 + T1@W11 + L(T1)@V21 + b) -> Bx
  k_spmm<<<gS, 256, 0, stream>>>(Bx, Bt, off, crow, cnrm);
  k_cheb<<<gG2, 256, 0, stream>>>(Bx, Bt, off, crow, cnrm,
                                  wq + OWD1, wq + OW11, wq + OV21, wf + 512, Bx);

  // ---- cheb2
  k_spmm<<<gS, 256, 0, stream>>>(Bx, Bt, off, crow, cnrm);
  k_cheb<<<gG2, 256, 0, stream>>>(Bx, Bt, off, crow, cnrm,
                                  wq + OWD2, wq + OW12, wq + OV22, wf + 640, Bx);

  // ---- postprocess: z2 = h3@Wpost + b -> Bt (+partials) ; BN+relu+dot -> y
  {
    MArgs a = {};
    a.A0 = Bx; a.W0T = wq + OWPOST;
    a.bias = wf + 768; a.out = Bt; a.gp = gp; a.part = part;
    k_mgemm<<<gG1, 256, 0, stream>>>(a);
  }
  k_redfin<<<8, 256, 0, stream>>>(part, wf + 896, wf + 1024, abB, gG1);
  k_out<<<(NN + 3) / 4, 256, 0, stream>>>(Bt, abB, wf + 1152, wf + 1280, gp, d_out);
}

// Round 2
// 757.726 us; speedup vs baseline: 1.0118x; 1.0118x over previous
//
#include <hip/hip_runtime.h>
#include <hip/hip_bf16.h>

using u16 = unsigned short;
using u32 = unsigned int;

#define NN 100000
#define NE 1000000

typedef __attribute__((ext_vector_type(8))) short bfrag;
typedef __attribute__((ext_vector_type(4))) float ffrag;

#define BF16ONE2 0x3F803F80u

__device__ __forceinline__ float bf2f(u16 u) { return __uint_as_float(((u32)u) << 16); }
__device__ __forceinline__ u16 f2bf(float f) {
  u32 x = __float_as_uint(f);
  return (u16)((x + 0x7fffu + ((x >> 16) & 1u)) >> 16);
}
__device__ __forceinline__ float rdv(const void* p, long i, int f) {
  return f ? bf2f(((const u16*)p)[i]) : ((const float*)p)[i];
}
__device__ __forceinline__ void acc8(float* a, uint4 v, float w) {
  a[0] = fmaf(w, __uint_as_float(v.x << 16), a[0]);
  a[1] = fmaf(w, __uint_as_float(v.x & 0xffff0000u), a[1]);
  a[2] = fmaf(w, __uint_as_float(v.y << 16), a[2]);
  a[3] = fmaf(w, __uint_as_float(v.y & 0xffff0000u), a[3]);
  a[4] = fmaf(w, __uint_as_float(v.z << 16), a[4]);
  a[5] = fmaf(w, __uint_as_float(v.z & 0xffff0000u), a[5]);
  a[6] = fmaf(w, __uint_as_float(v.w << 16), a[6]);
  a[7] = fmaf(w, __uint_as_float(v.w & 0xffff0000u), a[7]);
}

// wq (u16) element offsets
#define OWXT 0
#define OWPRE 16384
#define OWD1 32768
#define OW11 49152
#define OV21 65536
#define OWD2 81920
#define OW12 98304
#define OV22 114688
#define OWPOST 131072
#define OWET 147456

#define ASTRIDE 136
#define ESTRIDE 132

struct PrepArgs { const void* in[16]; };

__global__ void k_prep(PrepArgs a, const u32* __restrict__ gp, u16* __restrict__ wq,
                       float* __restrict__ wf) {
  int t = blockIdx.x * 256 + threadIdx.x;
  int f = (gp[0] == BF16ONE2) ? 1 : 0;
  if (t < 16384) {
    int o = t >> 7, k = t & 127;
    int ko = k * 128 + o;
    int ok = o * 128 + k;
    wq[OWXT + ok] = f2bf(rdv(a.in[0], ko, f));
    wq[OWPRE + ok] = f2bf(rdv(a.in[2], ko, f));
    float c0 = rdv(a.in[6], ko, f);
    float c1 = rdv(a.in[6], 16384 + ko, f);
    float c2 = rdv(a.in[6], 32768 + ko, f);
    wq[OWD1 + ok] = f2bf(c0 - c2);
    wq[OW11 + ok] = f2bf(c1);
    wq[OV21 + ok] = f2bf(2.f * c2);
    float d0 = rdv(a.in[8], ko, f);
    float d1 = rdv(a.in[8], 16384 + ko, f);
    float d2 = rdv(a.in[8], 32768 + ko, f);
    wq[OWD2 + ok] = f2bf(d0 - d2);
    wq[OW12 + ok] = f2bf(d1);
    wq[OV22 + ok] = f2bf(2.f * d2);
    wq[OWPOST + ok] = f2bf(rdv(a.in[10], ko, f));
  }
  if (t < 4096) {
    int o = t >> 5, k = t & 31;
    wq[OWET + o * 32 + k] = (k < 16) ? f2bf(rdv(a.in[0], (long)(128 + k) * 128 + o, f)) : (u16)0;
  }
  if (t < 1281) {
    int s = t >> 7, j = t & 127;
    const int map[11] = {1, 3, 4, 5, 7, 9, 11, 12, 13, 14, 15};
    wf[t] = rdv(a.in[map[s]], j, f);
  }
}

// ---------------- in-degree histogram: 8 edges/thread, deep atomic ILP ----------------
__global__ void k_hist(const int* __restrict__ ei, int* cnt) {
  long t = (long)blockIdx.x * 256 + threadIdx.x;
  long e0 = t * 8;
  if (e0 + 8 <= NE) {
    int4 c0 = *(const int4*)(ei + NE + e0);
    int4 c1 = *(const int4*)(ei + NE + e0 + 4);
    atomicAdd(&cnt[c0.x], 1);
    atomicAdd(&cnt[c0.y], 1);
    atomicAdd(&cnt[c0.z], 1);
    atomicAdd(&cnt[c0.w], 1);
    atomicAdd(&cnt[c1.x], 1);
    atomicAdd(&cnt[c1.y], 1);
    atomicAdd(&cnt[c1.z], 1);
    atomicAdd(&cnt[c1.w], 1);
  } else {
    for (long e = e0; e < NE; e++) atomicAdd(&cnt[ei[NE + e]], 1);
  }
}

// ---------------- exclusive scan ----------------
__global__ void k_scan1(const int* __restrict__ cnt, int* off, int* bsum) {
  __shared__ int s[1024];
  int t = threadIdx.x;
  int g = blockIdx.x * 1024 + t;
  int v = (g < NN) ? cnt[g] : 0;
  s[t] = v;
  __syncthreads();
  for (int st = 1; st < 1024; st <<= 1) {
    int x = (t >= st) ? s[t - st] : 0;
    __syncthreads();
    s[t] += x;
    __syncthreads();
  }
  if (g < NN) off[g] = s[t] - v;
  if (t == 1023) bsum[blockIdx.x] = s[t];
}

__global__ void k_scan23(int* off, const int* __restrict__ bsum, int* cur, int nb) {
  __shared__ int s[128];
  int t = threadIdx.x;
  int v = 0;
  if (t < 128) {
    v = (t < nb) ? bsum[t] : 0;
    s[t] = v;
  }
  __syncthreads();
  for (int st = 1; st < 128; st <<= 1) {
    int x = (t >= st && t < 128) ? s[t - st] : 0;
    __syncthreads();
    if (t < 128) s[t] += x;
    __syncthreads();
  }
  if (t < 128) s[t] -= v;
  __syncthreads();
  int pre = s[blockIdx.x];
  int g = blockIdx.x * 1024 + t;
  if (g < NN) {
    int o = off[g] + pre;
    off[g] = o;
    cur[g] = o;  // pre-seed CSR cursor: k_place skips the off[] load
  }
  if (g == 0) off[NN] = NE;
}

// ---------------- CSR placement + out-degree histogram (8 edges/thread) ----------------
__global__ void k_place(const int* __restrict__ ei, int* cur, int* deg,
                        int* __restrict__ crow, int* __restrict__ ceid) {
  long t = (long)blockIdx.x * 256 + threadIdx.x;
  long e0 = t * 8;
  if (e0 + 8 <= NE) {
    int4 r0 = *(const int4*)(ei + e0);
    int4 r1 = *(const int4*)(ei + e0 + 4);
    int4 c0 = *(const int4*)(ei + NE + e0);
    int4 c1 = *(const int4*)(ei + NE + e0 + 4);
    int r[8] = {r0.x, r0.y, r0.z, r0.w, r1.x, r1.y, r1.z, r1.w};
    int c[8] = {c0.x, c0.y, c0.z, c0.w, c1.x, c1.y, c1.z, c1.w};
    int p[8];
#pragma unroll
    for (int i = 0; i < 8; i++) p[i] = atomicAdd(&cur[c[i]], 1);
#pragma unroll
    for (int i = 0; i < 8; i++) atomicAdd(&deg[r[i]], 1);
#pragma unroll
    for (int i = 0; i < 8; i++) crow[p[i]] = r[i];
#pragma unroll
    for (int i = 0; i < 8; i++) ceid[p[i]] = (int)(e0 + i);
  } else {
    for (long e = e0; e < NE; e++) {
      int rr = ei[e], cc = ei[NE + e];
      int p = atomicAdd(&cur[cc], 1);
      atomicAdd(&deg[rr], 1);
      crow[p] = rr;
      ceid[p] = (int)e;
    }
  }
}

// ---------------- dis = rsqrt(out-degree) ----------------
__global__ void k_dis(const int* __restrict__ deg, float* __restrict__ dis) {
  int g = blockIdx.x * 256 + threadIdx.x;
  if (g >= NN) return;
  int d = deg[g];
  dis[g] = d > 0 ? rsqrtf((float)d) : 0.f;
}

// ------------- standalone SpMM (weighted): dst = L(src) -------------
__global__ __launch_bounds__(256) void k_spmm(const u16* __restrict__ src,
                                              u16* __restrict__ dst,
                                              const int* __restrict__ off,
                                              const int* __restrict__ crow,
                                              const float* __restrict__ cnorm) {
  int t = threadIdx.x;
  int node = blockIdx.x * 8 + (t >> 5);
  if (node >= NN) return;
  int l = t & 31;
  int half = l >> 4;
  int c = (l & 15) * 8;
  int p0 = off[node], p1 = off[node + 1];
  float a[8];
#pragma unroll
  for (int j = 0; j < 8; j++) a[j] = 0.f;
  const u16* sp = src + c;
  int p = p0 + half;
  for (; p + 6 < p1; p += 8) {
    int r0 = crow[p], r1 = crow[p + 2], r2 = crow[p + 4], r3 = crow[p + 6];
    float w0 = cnorm[p], w1 = cnorm[p + 2], w2 = cnorm[p + 4], w3 = cnorm[p + 6];
    uint4 v0 = *(const uint4*)(sp + (long)r0 * 128);
    uint4 v1 = *(const uint4*)(sp + (long)r1 * 128);
    uint4 v2 = *(const uint4*)(sp + (long)r2 * 128);
    uint4 v3 = *(const uint4*)(sp + (long)r3 * 128);
    acc8(a, v0, w0);
    acc8(a, v1, w1);
    acc8(a, v2, w2);
    acc8(a, v3, w3);
  }
  for (; p < p1; p += 2) acc8(a, *(const uint4*)(sp + (long)crow[p] * 128), cnorm[p]);
#pragma unroll
  for (int j = 0; j < 8; j++) a[j] += __shfl_xor(a[j], 16);
  if (half) return;
  uint4 o;
  o.x = (u32)f2bf(a[0]) | ((u32)f2bf(a[1]) << 16);
  o.y = (u32)f2bf(a[2]) | ((u32)f2bf(a[3]) << 16);
  o.z = (u32)f2bf(a[4]) | ((u32)f2bf(a[5]) << 16);
  o.w = (u32)f2bf(a[6]) | ((u32)f2bf(a[7]) << 16);
  *(uint4*)(dst + (long)node * 128 + c) = o;
}

// ------------- gather L(src) (or segsum) for 64 rows into LDS (ASTRIDE layout) -------------
template <int WEIGHTED>
__device__ __forceinline__ void gather_lds(u16* sA, const u16* __restrict__ src,
                                           const int* __restrict__ off,
                                           const int* __restrict__ crow,
                                           const float* __restrict__ cnorm, int r0) {
  int tid = threadIdx.x;
  int grp = tid >> 4;      // 16 groups of 16 lanes
  int c = (tid & 15) * 8;  // 8 cols per lane
  const u16* sp = src + c;
#pragma unroll
  for (int i = 0; i < 4; i++) {
    int nl = grp * 4 + i;
    int node = r0 + nl;
    float a[8];
#pragma unroll
    for (int j = 0; j < 8; j++) a[j] = 0.f;
    if (node < NN) {
      int p0 = off[node], p1 = off[node + 1];
      int p = p0;
      for (; p + 4 <= p1; p += 4) {
        int r0i = crow[p], r1i = crow[p + 1], r2i = crow[p + 2], r3i = crow[p + 3];
        float w0 = WEIGHTED ? cnorm[p] : 1.f;
        float w1 = WEIGHTED ? cnorm[p + 1] : 1.f;
        float w2 = WEIGHTED ? cnorm[p + 2] : 1.f;
        float w3 = WEIGHTED ? cnorm[p + 3] : 1.f;
        uint4 v0 = *(const uint4*)(sp + (long)r0i * 128);
        uint4 v1 = *(const uint4*)(sp + (long)r1i * 128);
        uint4 v2 = *(const uint4*)(sp + (long)r2i * 128);
        uint4 v3 = *(const uint4*)(sp + (long)r3i * 128);
        acc8(a, v0, w0);
        acc8(a, v1, w1);
        acc8(a, v2, w2);
        acc8(a, v3, w3);
      }
      for (; p < p1; p++)
        acc8(a, *(const uint4*)(sp + (long)crow[p] * 128), WEIGHTED ? cnorm[p] : 1.f);
    }
    uint4 o;
    o.x = (u32)f2bf(a[0]) | ((u32)f2bf(a[1]) << 16);
    o.y = (u32)f2bf(a[2]) | ((u32)f2bf(a[3]) << 16);
    o.z = (u32)f2bf(a[4]) | ((u32)f2bf(a[5]) << 16);
    o.w = (u32)f2bf(a[6]) | ((u32)f2bf(a[7]) << 16);
    *(uint4*)(sA + nl * ASTRIDE + c) = o;
  }
}

// ------------- edge_attr segment-sum ([N,16]) + cnorm precompute -------------
__global__ __launch_bounds__(256) void k_asum(const void* __restrict__ eattr,
                                              const u32* __restrict__ gp,
                                              u16* __restrict__ asum,
                                              const int* __restrict__ off,
                                              const int* __restrict__ ceid,
                                              const int* __restrict__ crow,
                                              const float* __restrict__ dis,
                                              float* __restrict__ cnorm) {
  int t = blockIdx.x * 256 + threadIdx.x;
  int node = t >> 4;
  if (node >= NN) return;
  int j = t & 15;
  int p0 = off[node], p1 = off[node + 1];
  float ndis = -dis[node];
  for (int p = p0 + j; p < p1; p += 16) cnorm[p] = ndis * dis[crow[p]];
  float a = 0.f;
  if (gp[0] == BF16ONE2) {
    const u16* e16 = (const u16*)eattr;
    int p = p0;
    for (; p + 4 <= p1; p += 4) {
      float v0 = bf2f(e16[(long)ceid[p] * 16 + j]);
      float v1 = bf2f(e16[(long)ceid[p + 1] * 16 + j]);
      float v2 = bf2f(e16[(long)ceid[p + 2] * 16 + j]);
      float v3 = bf2f(e16[(long)ceid[p + 3] * 16 + j]);
      a += v0 + v1 + v2 + v3;
    }
    for (; p < p1; p++) a += bf2f(e16[(long)ceid[p] * 16 + j]);
  } else {
    const float* e32 = (const float*)eattr;
    int p = p0;
    for (; p + 4 <= p1; p += 4) {
      float v0 = e32[(long)ceid[p] * 16 + j];
      float v1 = e32[(long)ceid[p + 1] * 16 + j];
      float v2 = e32[(long)ceid[p + 2] * 16 + j];
      float v3 = e32[(long)ceid[p + 3] * 16 + j];
      a += v0 + v1 + v2 + v3;
    }
    for (; p < p1; p++) a += e32[(long)ceid[p] * 16 + j];
  }
  asum[(long)node * 16 + j] = f2bf(a);
}

// ------------- plain MFMA GEMM (ROWS=128): out = A0@W0T^T + bias (+partials) -------------
struct MArgs {
  const void* A0; const u16* W0T; int a0raw;
  const float* bias;
  u16* out;
  const u32* gp;
  float* part;
};

__global__ __launch_bounds__(256) void k_mgemm(MArgs m) {
  constexpr int ROWS = 128, RT = 8, TPR = 2, SEGW = 64;
  __shared__ __align__(16) u16 sA[ROWS * ASTRIDE];
  int tid = threadIdx.x;
  int wv = tid >> 6, lane = tid & 63;
  int col16 = lane & 15, quad = lane >> 4;
  int r0 = blockIdx.x * ROWS;

  ffrag acc[RT * 2];
#pragma unroll
  for (int i = 0; i < RT * 2; i++)
#pragma unroll
    for (int g = 0; g < 4; g++) acc[i][g] = 0.f;

  {
    int row = tid / TPR, seg = tid % TPR;
    int ra = r0 + row;
    if (ra >= NN) ra = NN - 1;
    bool f32a = m.a0raw && (m.gp[0] != BF16ONE2);
    if (f32a) {
      const float* gs = (const float*)m.A0 + (long)ra * 128 + seg * SEGW;
      u32* lp = (u32*)(sA + row * ASTRIDE + seg * SEGW);
#pragma unroll
      for (int e = 0; e < SEGW / 8; e++) {
        float4 v0 = *(const float4*)(gs + e * 8);
        float4 v1 = *(const float4*)(gs + e * 8 + 4);
        lp[e * 4 + 0] = (u32)f2bf(v0.x) | ((u32)f2bf(v0.y) << 16);
        lp[e * 4 + 1] = (u32)f2bf(v0.z) | ((u32)f2bf(v0.w) << 16);
        lp[e * 4 + 2] = (u32)f2bf(v1.x) | ((u32)f2bf(v1.y) << 16);
        lp[e * 4 + 3] = (u32)f2bf(v1.z) | ((u32)f2bf(v1.w) << 16);
      }
    } else {
      const u16* gs = (const u16*)m.A0 + (long)ra * 128 + seg * SEGW;
      uint4* lp = (uint4*)(sA + row * ASTRIDE + seg * SEGW);
#pragma unroll
      for (int e = 0; e < SEGW / 8; e++) lp[e] = *(const uint4*)(gs + e * 8);
    }
  }
  bfrag b0[2][4];
#pragma unroll
  for (int c = 0; c < 2; c++)
#pragma unroll
    for (int kb = 0; kb < 4; kb++)
      b0[c][kb] = *(const bfrag*)(m.W0T + (long)(wv * 32 + c * 16 + col16) * 128 + kb * 32 + quad * 8);
  __syncthreads();
#pragma unroll
  for (int kb = 0; kb < 4; kb++)
#pragma unroll
    for (int rt = 0; rt < RT; rt++) {
      bfrag af = *(const bfrag*)(sA + (rt * 16 + col16) * ASTRIDE + kb * 32 + quad * 8);
      acc[rt * 2 + 0] = __builtin_amdgcn_mfma_f32_16x16x32_bf16(af, b0[0][kb], acc[rt * 2 + 0], 0, 0, 0);
      acc[rt * 2 + 1] = __builtin_amdgcn_mfma_f32_16x16x32_bf16(af, b0[1][kb], acc[rt * 2 + 1], 0, 0, 0);
    }
  __syncthreads();
#pragma unroll
  for (int rt = 0; rt < RT; rt++)
#pragma unroll
    for (int c = 0; c < 2; c++) {
      int col = wv * 32 + c * 16 + col16;
      float bj = m.bias ? m.bias[col] : 0.f;
#pragma unroll
      for (int g = 0; g < 4; g++)
        sA[(rt * 16 + quad * 4 + g) * ESTRIDE + col] = f2bf(acc[rt * 2 + c][g] + bj);
    }
  __syncthreads();
  {
    int rr = tid / TPR, d = tid % TPR;
    int rowg = r0 + rr;
    if (rowg < NN) {
      const u16* sp2 = sA + rr * ESTRIDE + d * 64;
      uint4* o = (uint4*)(m.out + (long)rowg * 128 + d * 64);
#pragma unroll
      for (int e = 0; e < 8; e++) {
        const uint2* s2 = (const uint2*)(sp2 + e * 8);
        uint2 lo = s2[0], hi = s2[1];
        o[e] = make_uint4(lo.x, lo.y, hi.x, hi.y);
      }
    }
  }
  if (m.part) {
    __shared__ float ps[256], pq[256];
    int col = tid & 127, hf = tid >> 7;
    float s = 0.f, q = 0.f;
#pragma unroll
    for (int r = 0; r < 64; r++) {
      int rr = hf * 64 + r;
      if (r0 + rr < NN) {
        float v = bf2f(sA[rr * ESTRIDE + col]);
        s += v;
        q += v * v;
      }
    }
    ps[tid] = s;
    pq[tid] = q;
    __syncthreads();
    if (tid < 128) {
      m.part[(long)blockIdx.x * 256 + tid] = ps[tid] + ps[tid + 128];
      m.part[(long)blockIdx.x * 256 + 128 + tid] = pq[tid] + pq[tid + 128];
    }
  }
}

// ------------- fused: S-gather + ET GEMM + mean + preprocess GEMM -------------
__global__ __launch_bounds__(256) void k_etpre(const u16* __restrict__ Xg,
                                               const u16* __restrict__ asum,
                                               const u16* __restrict__ Wet,
                                               const u16* __restrict__ Wpre,
                                               const float* __restrict__ b_int,
                                               const float* __restrict__ b_pre,
                                               const int* __restrict__ off,
                                               const int* __restrict__ crow,
                                               u16* __restrict__ out, float* part) {
  __shared__ __align__(16) u16 sA[64 * ASTRIDE];
  int tid = threadIdx.x;
  int wv = tid >> 6, lane = tid & 63;
  int col16 = lane & 15, quad = lane >> 4;
  int r0 = blockIdx.x * 64;

  // stage asum [64 x 16] into cols 0..15, zero 16..31
  {
    int row = tid >> 2, seg = tid & 3;
    int ra = r0 + row;
    if (ra >= NN) ra = NN - 1;
    if (seg < 2)
      *(uint4*)(sA + row * ASTRIDE + seg * 8) = *(const uint4*)(asum + (long)ra * 16 + seg * 8);
    else
      *(uint4*)(sA + row * ASTRIDE + seg * 8) = make_uint4(0, 0, 0, 0);
  }
  bfrag be[2];
#pragma unroll
  for (int c = 0; c < 2; c++)
    be[c] = *(const bfrag*)(Wet + (long)(wv * 32 + c * 16 + col16) * 32 + quad * 8);
  __syncthreads();
  ffrag accE[8];
#pragma unroll
  for (int i = 0; i < 8; i++)
#pragma unroll
    for (int g = 0; g < 4; g++) accE[i][g] = 0.f;
#pragma unroll
  for (int rt = 0; rt < 4; rt++) {
    bfrag af = *(const bfrag*)(sA + (rt * 16 + col16) * ASTRIDE + quad * 8);
    accE[rt * 2 + 0] = __builtin_amdgcn_mfma_f32_16x16x32_bf16(af, be[0], accE[rt * 2 + 0], 0, 0, 0);
    accE[rt * 2 + 1] = __builtin_amdgcn_mfma_f32_16x16x32_bf16(af, be[1], accE[rt * 2 + 1], 0, 0, 0);
  }
  __syncthreads();
  // gather S = segsum(Xg) into sA (full 128 cols)
  gather_lds<0>(sA, Xg, off, crow, nullptr, r0);
  __syncthreads();
  // h = (accE + S + cnt*b)/max(cnt,1)  -> in-place at C-layout positions
  // cnt[r] == off[r+1]-off[r] (in-degree)
#pragma unroll
  for (int rt = 0; rt < 4; rt++)
#pragma unroll
    for (int g = 0; g < 4; g++) {
      int rr = rt * 16 + quad * 4 + g;
      int r = r0 + rr;
      int cc = (r < NN) ? off[r + 1] - off[r] : 0;
      float inv = 1.f / (float)(cc > 1 ? cc : 1);
#pragma unroll
      for (int c = 0; c < 2; c++) {
        int col = wv * 32 + c * 16 + col16;
        float bj = b_int[col];
        float v = accE[rt * 2 + c][g] + bf2f(sA[rr * ASTRIDE + col]);
        v = (v + (float)cc * bj) * inv;
        sA[rr * ASTRIDE + col] = f2bf(v);
      }
    }
  bfrag b1[2][4];
#pragma unroll
  for (int c = 0; c < 2; c++)
#pragma unroll
    for (int kb = 0; kb < 4; kb++)
      b1[c][kb] = *(const bfrag*)(Wpre + (long)(wv * 32 + c * 16 + col16) * 128 + kb * 32 + quad * 8);
  __syncthreads();
  ffrag a2[8];
#pragma unroll
  for (int i = 0; i < 8; i++)
#pragma unroll
    for (int g = 0; g < 4; g++) a2[i][g] = 0.f;
#pragma unroll
  for (int kb = 0; kb < 4; kb++)
#pragma unroll
    for (int rt = 0; rt < 4; rt++) {
      bfrag af = *(const bfrag*)(sA + (rt * 16 + col16) * ASTRIDE + kb * 32 + quad * 8);
      a2[rt * 2 + 0] = __builtin_amdgcn_mfma_f32_16x16x32_bf16(af, b1[0][kb], a2[rt * 2 + 0], 0, 0, 0);
      a2[rt * 2 + 1] = __builtin_amdgcn_mfma_f32_16x16x32_bf16(af, b1[1][kb], a2[rt * 2 + 1], 0, 0, 0);
    }
  __syncthreads();
#pragma unroll
  for (int rt = 0; rt < 4; rt++)
#pragma unroll
    for (int c = 0; c < 2; c++) {
      int col = wv * 32 + c * 16 + col16;
      float bj = b_pre[col];
#pragma unroll
      for (int g = 0; g < 4; g++)
        sA[(rt * 16 + quad * 4 + g) * ESTRIDE + col] = f2bf(a2[rt * 2 + c][g] + bj);
    }
  __syncthreads();
  {
    int rr = tid >> 2, d = tid & 3;
    int rowg = r0 + rr;
    if (rowg < NN) {
      const u16* sp2 = sA + rr * ESTRIDE + d * 32;
      uint4* o = (uint4*)(out + (long)rowg * 128 + d * 32);
#pragma unroll
      for (int e = 0; e < 4; e++) {
        const uint2* s2 = (const uint2*)(sp2 + e * 8);
        uint2 lo = s2[0], hi = s2[1];
        o[e] = make_uint4(lo.x, lo.y, hi.x, hi.y);
      }
    }
  }
  {
    __shared__ float ps[256], pq[256];
    int col = tid & 127, hf = tid >> 7;
    float s = 0.f, q = 0.f;
#pragma unroll
    for (int r = 0; r < 32; r++) {
      int rr = hf * 32 + r;
      if (r0 + rr < NN) {
        float v = bf2f(sA[rr * ESTRIDE + col]);
        s += v;
        q += v * v;
      }
    }
    ps[tid] = s;
    pq[tid] = q;
    __syncthreads();
    if (tid < 128) {
      part[(long)blockIdx.x * 256 + tid] = ps[tid] + ps[tid + 128];
      part[(long)blockIdx.x * 256 + 128 + tid] = pq[tid] + pq[tid + 128];
    }
  }
}

// ------------- fused cheb layer: out = relu(hb@WD + T1@W1 + L(T1)@V2 + b), in-place over hb -------------
__global__ __launch_bounds__(256) void k_cheb(const u16* __restrict__ hb,
                                              const u16* __restrict__ T1,
                                              const int* __restrict__ off,
                                              const int* __restrict__ crow,
                                              const float* __restrict__ cnorm,
                                              const u16* __restrict__ WD,
                                              const u16* __restrict__ W1,
                                              const u16* __restrict__ V2,
                                              const float* __restrict__ bias,
                                              u16* __restrict__ out) {
  __shared__ __align__(16) u16 sA[64 * ASTRIDE];
  int tid = threadIdx.x;
  int wv = tid >> 6, lane = tid & 63;
  int col16 = lane & 15, quad = lane >> 4;
  int r0 = blockIdx.x * 64;

  ffrag acc[8];
#pragma unroll
  for (int i = 0; i < 8; i++)
#pragma unroll
    for (int g = 0; g < 4; g++) acc[i][g] = 0.f;

  // phase 1: gather L(T1) -> sA ; MFMA with V2
  gather_lds<1>(sA, T1, off, crow, cnorm, r0);
  bfrag bv[2][4];
#pragma unroll
  for (int c = 0; c < 2; c++)
#pragma unroll
    for (int kb = 0; kb < 4; kb++)
      bv[c][kb] = *(const bfrag*)(V2 + (long)(wv * 32 + c * 16 + col16) * 128 + kb * 32 + quad * 8);
  __syncthreads();
#pragma unroll
  for (int kb = 0; kb < 4; kb++)
#pragma unroll
    for (int rt = 0; rt < 4; rt++) {
      bfrag af = *(const bfrag*)(sA + (rt * 16 + col16) * ASTRIDE + kb * 32 + quad * 8);
      acc[rt * 2 + 0] = __builtin_amdgcn_mfma_f32_16x16x32_bf16(af, bv[0][kb], acc[rt * 2 + 0], 0, 0, 0);
      acc[rt * 2 + 1] = __builtin_amdgcn_mfma_f32_16x16x32_bf16(af, bv[1][kb], acc[rt * 2 + 1], 0, 0, 0);
    }
  __syncthreads();

  // phase 2: stage hb own rows ; MFMA with WD
  {
    int row = tid >> 2, seg = tid & 3;
    int ra = r0 + row;
    if (ra >= NN) ra = NN - 1;
    const u16* gs = hb + (long)ra * 128 + seg * 32;
    uint4* lp = (uint4*)(sA + row * ASTRIDE + seg * 32);
#pragma unroll
    for (int e = 0; e < 4; e++) lp[e] = *(const uint4*)(gs + e * 8);
  }
#pragma unroll
  for (int c = 0; c < 2; c++)
#pragma unroll
    for (int kb = 0; kb < 4; kb++)
      bv[c][kb] = *(const bfrag*)(WD + (long)(wv * 32 + c * 16 + col16) * 128 + kb * 32 + quad * 8);
  __syncthreads();
#pragma unroll
  for (int kb = 0; kb < 4; kb++)
#pragma unroll
    for (int rt = 0; rt < 4; rt++) {
      bfrag af = *(const bfrag*)(sA + (rt * 16 + col16) * ASTRIDE + kb * 32 + quad * 8);
      acc[rt * 2 + 0] = __builtin_amdgcn_mfma_f32_16x16x32_bf16(af, bv[0][kb], acc[rt * 2 + 0], 0, 0, 0);
      acc[rt * 2 + 1] = __builtin_amdgcn_mfma_f32_16x16x32_bf16(af, bv[1][kb], acc[rt * 2 + 1], 0, 0, 0);
    }
  __syncthreads();

  // phase 3: stage T1 own rows ; MFMA with W1
  {
    int row = tid >> 2, seg = tid & 3;
    int ra = r0 + row;
    if (ra >= NN) ra = NN - 1;
    const u16* gs = T1 + (long)ra * 128 + seg * 32;
    uint4* lp = (uint4*)(sA + row * ASTRIDE + seg * 32);
#pragma unroll
    for (int e = 0; e < 4; e++) lp[e] = *(const uint4*)(gs + e * 8);
  }
#pragma unroll
  for (int c = 0; c < 2; c++)
#pragma unroll
    for (int kb = 0; kb < 4; kb++)
      bv[c][kb] = *(const bfrag*)(W1 + (long)(wv * 32 + c * 16 + col16) * 128 + kb * 32 + quad * 8);
  __syncthreads();
#pragma unroll
  for (int kb = 0; kb < 4; kb++)
#pragma unroll
    for (int rt = 0; rt < 4; rt++) {
      bfrag af = *(const bfrag*)(sA + (rt * 16 + col16) * ASTRIDE + kb * 32 + quad * 8);
      acc[rt * 2 + 0] = __builtin_amdgcn_mfma_f32_16x16x32_bf16(af, bv[0][kb], acc[rt * 2 + 0], 0, 0, 0);
      acc[rt * 2 + 1] = __builtin_amdgcn_mfma_f32_16x16x32_bf16(af, bv[1][kb], acc[rt * 2 + 1], 0, 0, 0);
    }
  __syncthreads();

  // epilogue: +bias, relu, repack, store
#pragma unroll
  for (int rt = 0; rt < 4; rt++)
#pragma unroll
    for (int c = 0; c < 2; c++) {
      int col = wv * 32 + c * 16 + col16;
      float bj = bias[col];
#pragma unroll
      for (int g = 0; g < 4; g++)
        sA[(rt * 16 + quad * 4 + g) * ESTRIDE + col] = f2bf(fmaxf(acc[rt * 2 + c][g] + bj, 0.f));
    }
  __syncthreads();
  {
    int rr = tid >> 2, d = tid & 3;
    int rowg = r0 + rr;
    if (rowg < NN) {
      const u16* sp2 = sA + rr * ESTRIDE + d * 32;
      uint4* o = (uint4*)(out + (long)rowg * 128 + d * 32);
#pragma unroll
      for (int e = 0; e < 4; e++) {
        const uint2* s2 = (const uint2*)(sp2 + e * 8);
        uint2 lo = s2[0], hi = s2[1];
        o[e] = make_uint4(lo.x, lo.y, hi.x, hi.y);
      }
    }
  }
}

// ------------- reduce partials + BN finalize fused -------------
__global__ void k_redfin(const float* __restrict__ part, const float* __restrict__ gamma,
                         const float* __restrict__ beta, float* ab, int nblk) {
  int tid = threadIdx.x;
  int col = blockIdx.x * 16 + (tid & 15);
  int ch = tid >> 4;
  float s = 0.f, q = 0.f;
  for (int b = ch; b < nblk; b += 16) {
    s += part[(long)b * 256 + col];
    q += part[(long)b * 256 + 128 + col];
  }
  __shared__ float sh[256], qh[256];
  sh[tid] = s;
  qh[tid] = q;
  __syncthreads();
  if (tid < 16) {
    float ts = 0.f, tq = 0.f;
#pragma unroll
    for (int i = 0; i < 16; i++) {
      ts += sh[i * 16 + tid];
      tq += qh[i * 16 + tid];
    }
    int j = blockIdx.x * 16 + tid;
    float m = ts * (1.f / (float)NN);
    float v = fmaxf(tq * (1.f / (float)NN) - m * m, 0.f);
    float a = gamma[j] * rsqrtf(v + 1e-5f);
    ab[j] = a;
    ab[128 + j] = beta[j] - m * a;
  }
}

__global__ void k_bnrelu(const u16* __restrict__ z, u16* __restrict__ out,
                         const float* __restrict__ ab) {
  long idx = (long)blockIdx.x * 256 + threadIdx.x;
  long t = idx * 2;
  if (t >= (long)NN * 128) return;
  int col = (int)(t & 127);
  u32 v = *(const u32*)(z + t);
  float f0 = fmaxf(__uint_as_float(v << 16) * ab[col] + ab[128 + col], 0.f);
  float f1 = fmaxf(__uint_as_float(v & 0xffff0000u) * ab[col + 1] + ab[129 + col], 0.f);
  *(u32*)(out + t) = (u32)f2bf(f0) | ((u32)f2bf(f1) << 16);
}

__global__ void k_out(const u16* __restrict__ z, const float* __restrict__ ab,
                      const float* __restrict__ wout, const float* __restrict__ bout,
                      const u32* __restrict__ gp, void* __restrict__ y) {
  int node = blockIdx.x * 4 + (threadIdx.x >> 6);
  if (node >= NN) return;
  int lane = threadIdx.x & 63;
  float s = 0.f;
#pragma unroll
  for (int c = lane; c < 128; c += 64) {
    float zz = bf2f(z[(long)node * 128 + c]);
    float h = fmaxf(ab[c] * zz + ab[128 + c], 0.f);
    s += h * wout[c];
  }
#pragma unroll
  for (int o = 32; o > 0; o >>= 1) s += __shfl_down(s, o);
  if (lane == 0) {
    float r = s + bout[0];
    if (gp[0] == BF16ONE2) ((u16*)y)[node] = f2bf(r);
    else ((float*)y)[node] = r;
  }
}

extern "C" void kernel_launch(void* const* d_in, const int* in_sizes, int n_in,
                              void* d_out, int out_size, void* d_ws, size_t ws_size,
                              hipStream_t stream) {
  const void* x = d_in[0];
  const int* ei = (const int*)d_in[1];
  const void* eattr = d_in[2];
  const u32* gp = (const u32*)d_in[7];
  (void)in_sizes; (void)n_in; (void)out_size; (void)ws_size;

  char* w = (char*)d_ws;
  size_t p = 0;
  auto alloc = [&](size_t b) { size_t r = p; p += (b + 255) & ~(size_t)255; return r; };
  size_t o_cnt = alloc((size_t)NN * 4);
  size_t o_deg = alloc((size_t)NN * 4);
  size_t o_zero_end = p;
  size_t o_cur = alloc((size_t)NN * 4);
  size_t o_dis = alloc((size_t)NN * 4);
  size_t o_off = alloc((size_t)(NN + 1) * 4);
  size_t o_bsum = alloc(1024 * 4);
  size_t o_ab = alloc(512 * 4);
  size_t o_wq = alloc((size_t)151552 * 2);
  size_t o_wf = alloc((size_t)1281 * 4);
  size_t o_crow = alloc((size_t)NE * 4);
  size_t o_cnrm = alloc((size_t)NE * 4);
  size_t o_asum = alloc((size_t)NN * 16 * 2);
  size_t o_part = alloc((size_t)1563 * 256 * 4);
  size_t o_Bx = alloc((size_t)NN * 128 * 2);
  size_t o_Bt = alloc((size_t)NN * 128 * 2);

  int* cnt = (int*)(w + o_cnt);
  int* deg = (int*)(w + o_deg);
  int* cur = (int*)(w + o_cur);
  float* dis = (float*)(w + o_dis);
  int* off = (int*)(w + o_off);
  int* bsum = (int*)(w + o_bsum);
  float* abA = (float*)(w + o_ab);
  float* abB = abA + 256;
  u16* wq = (u16*)(w + o_wq);
  float* wf = (float*)(w + o_wf);
  int* crow = (int*)(w + o_crow);
  float* cnrm = (float*)(w + o_cnrm);
  u16* asum = (u16*)(w + o_asum);
  float* part = (float*)(w + o_part);
  u16* Bx = (u16*)(w + o_Bx);
  u16* Bt = (u16*)(w + o_Bt);
  int* ceid = (int*)Bt;  // transient: dead before Bt first written

  hipMemsetAsync(w + o_cnt, 0, o_zero_end - o_cnt, stream);  // zero cnt+deg

  int gH = (NE / 8 + 255) / 256;  // 489: 8 edges/thread
  int nb = (NN + 1023) / 1024;
  int gS = (NN + 7) / 8;
  int gN = (NN + 255) / 256;
  int gG1 = (NN + 127) / 128;  // 782
  int gG2 = (NN + 63) / 64;    // 1563

  {
    PrepArgs a;
    for (int i = 0; i < 16; i++) a.in[i] = d_in[3 + i];
    k_prep<<<64, 256, 0, stream>>>(a, gp, wq, wf);
  }

  k_hist<<<gH, 256, 0, stream>>>(ei, cnt);
  k_scan1<<<nb, 1024, 0, stream>>>(cnt, off, bsum);
  k_scan23<<<nb, 1024, 0, stream>>>(off, bsum, cur, nb);
  k_place<<<gH, 256, 0, stream>>>(ei, cur, deg, crow, ceid);
  k_dis<<<gN, 256, 0, stream>>>(deg, dis);
  k_asum<<<(NN * 16 + 255) / 256, 256, 0, stream>>>(eattr, gp, asum, off, ceid, crow, dis, cnrm);

  // ---- Xg = x @ Wx -> Bx (must materialize: gather src)
  {
    MArgs a = {};
    a.A0 = x; a.W0T = wq + OWXT; a.a0raw = 1;
    a.out = Bx; a.gp = gp;
    k_mgemm<<<gG1, 256, 0, stream>>>(a);
  }
  // ---- fused: S = segsum(Xg) (gather in-kernel), h = (S+asum@We+cnt*b)/cnt, z = h@Wpre+b -> Bt
  k_etpre<<<gG2, 256, 0, stream>>>(Bx, asum, wq + OWET, wq + OWPRE, wf + 0, wf + 128,
                                   off, crow, Bt, part);
  k_redfin<<<8, 256, 0, stream>>>(part, wf + 256, wf + 384, abA, gG2);
  // ---- hb = relu(bn(z)): Bt -> Bx
  k_bnrelu<<<(int)(((long)NN * 128 / 2 + 255) / 256), 256, 0, stream>>>(Bt, Bx, abA);

  // ---- cheb1: T1 = L(hb) -> Bt ; fused h2 = relu(hb@WD1 + T1@W11 + L(T1)@V21 + b) -> Bx
  k_spmm<<<gS, 256, 0, stream>>>(Bx, Bt, off, crow, cnrm);
  k_cheb<<<gG2, 256, 0, stream>>>(Bx, Bt, off, crow, cnrm,
                                  wq + OWD1, wq + OW11, wq + OV21, wf + 512, Bx);

  // ---- cheb2
  k_spmm<<<gS, 256, 0, stream>>>(Bx, Bt, off, crow, cnrm);
  k_cheb<<<gG2, 256, 0, stream>>>(Bx, Bt, off, crow, cnrm,
                                  wq + OWD2, wq + OW12, wq + OV22, wf + 640, Bx);

  // ---- postprocess: z2 = h3@Wpost + b -> Bt (+partials) ; BN+relu+dot -> y
  {
    MArgs a = {};
    a.A0 = Bx; a.W0T = wq + OWPOST;
    a.bias = wf + 768; a.out = Bt; a.gp = gp; a.part = part;
    k_mgemm<<<gG1, 256, 0, stream>>>(a);
  }
  k_redfin<<<8, 256, 0, stream>>>(part, wf + 896, wf + 1024, abB, gG1);
  k_out<<<(NN + 3) / 4, 256, 0, stream>>>(Bt, abB, wf + 1152, wf + 1280, gp, d_out);
}

// Round 4
// 739.418 us; speedup vs baseline: 1.0369x; 1.0248x over previous
//
#include <hip/hip_runtime.h>
#include <hip/hip_bf16.h>

using u16 = unsigned short;
using u32 = unsigned int;

#define NN 100000
#define NE 1000000

typedef __attribute__((ext_vector_type(8))) short bfrag;
typedef __attribute__((ext_vector_type(4))) float ffrag;

#define BF16ONE2 0x3F803F80u

__device__ __forceinline__ float bf2f(u16 u) { return __uint_as_float(((u32)u) << 16); }
__device__ __forceinline__ u16 f2bf(float f) {
  u32 x = __float_as_uint(f);
  return (u16)((x + 0x7fffu + ((x >> 16) & 1u)) >> 16);
}
__device__ __forceinline__ float rdv(const void* p, long i, int f) {
  return f ? bf2f(((const u16*)p)[i]) : ((const float*)p)[i];
}
__device__ __forceinline__ void acc8(float* a, uint4 v, float w) {
  a[0] = fmaf(w, __uint_as_float(v.x << 16), a[0]);
  a[1] = fmaf(w, __uint_as_float(v.x & 0xffff0000u), a[1]);
  a[2] = fmaf(w, __uint_as_float(v.y << 16), a[2]);
  a[3] = fmaf(w, __uint_as_float(v.y & 0xffff0000u), a[3]);
  a[4] = fmaf(w, __uint_as_float(v.z << 16), a[4]);
  a[5] = fmaf(w, __uint_as_float(v.z & 0xffff0000u), a[5]);
  a[6] = fmaf(w, __uint_as_float(v.w << 16), a[6]);
  a[7] = fmaf(w, __uint_as_float(v.w & 0xffff0000u), a[7]);
}
// BN+ReLU applied to source value before weighted accumulate
__device__ __forceinline__ void acc8bn(float* a, uint4 v, float w, const float* A,
                                       const float* Bb) {
  float x;
  x = __uint_as_float(v.x << 16);
  a[0] = fmaf(w, fmaxf(fmaf(A[0], x, Bb[0]), 0.f), a[0]);
  x = __uint_as_float(v.x & 0xffff0000u);
  a[1] = fmaf(w, fmaxf(fmaf(A[1], x, Bb[1]), 0.f), a[1]);
  x = __uint_as_float(v.y << 16);
  a[2] = fmaf(w, fmaxf(fmaf(A[2], x, Bb[2]), 0.f), a[2]);
  x = __uint_as_float(v.y & 0xffff0000u);
  a[3] = fmaf(w, fmaxf(fmaf(A[3], x, Bb[3]), 0.f), a[3]);
  x = __uint_as_float(v.z << 16);
  a[4] = fmaf(w, fmaxf(fmaf(A[4], x, Bb[4]), 0.f), a[4]);
  x = __uint_as_float(v.z & 0xffff0000u);
  a[5] = fmaf(w, fmaxf(fmaf(A[5], x, Bb[5]), 0.f), a[5]);
  x = __uint_as_float(v.w << 16);
  a[6] = fmaf(w, fmaxf(fmaf(A[6], x, Bb[6]), 0.f), a[6]);
  x = __uint_as_float(v.w & 0xffff0000u);
  a[7] = fmaf(w, fmaxf(fmaf(A[7], x, Bb[7]), 0.f), a[7]);
}

// wq (u16) element offsets
#define OWXT 0
#define OWPRE 16384
#define OWD1 32768
#define OW11 49152
#define OV21 65536
#define OWD2 81920
#define OW12 98304
#define OV22 114688
#define OWPOST 131072
#define OWET 147456

#define ASTRIDE 136
#define ESTRIDE 132

struct PrepArgs { const void* in[16]; };

__global__ void k_prep(PrepArgs a, const u32* __restrict__ gp, u16* __restrict__ wq,
                       float* __restrict__ wf) {
  int t = blockIdx.x * 256 + threadIdx.x;
  int f = (gp[0] == BF16ONE2) ? 1 : 0;
  if (t < 16384) {
    int o = t >> 7, k = t & 127;
    int ko = k * 128 + o;
    int ok = o * 128 + k;
    wq[OWXT + ok] = f2bf(rdv(a.in[0], ko, f));
    wq[OWPRE + ok] = f2bf(rdv(a.in[2], ko, f));
    float c0 = rdv(a.in[6], ko, f);
    float c1 = rdv(a.in[6], 16384 + ko, f);
    float c2 = rdv(a.in[6], 32768 + ko, f);
    wq[OWD1 + ok] = f2bf(c0 - c2);
    wq[OW11 + ok] = f2bf(c1);
    wq[OV21 + ok] = f2bf(2.f * c2);
    float d0 = rdv(a.in[8], ko, f);
    float d1 = rdv(a.in[8], 16384 + ko, f);
    float d2 = rdv(a.in[8], 32768 + ko, f);
    wq[OWD2 + ok] = f2bf(d0 - d2);
    wq[OW12 + ok] = f2bf(d1);
    wq[OV22 + ok] = f2bf(2.f * d2);
    wq[OWPOST + ok] = f2bf(rdv(a.in[10], ko, f));
  }
  if (t < 4096) {
    int o = t >> 5, k = t & 31;
    wq[OWET + o * 32 + k] = (k < 16) ? f2bf(rdv(a.in[0], (long)(128 + k) * 128 + o, f)) : (u16)0;
  }
  if (t < 1281) {
    int s = t >> 7, j = t & 127;
    const int map[11] = {1, 3, 4, 5, 7, 9, 11, 12, 13, 14, 15};
    wf[t] = rdv(a.in[map[s]], j, f);
  }
}

// ---------------- in-degree histogram: 8 edges/thread, deep atomic ILP ----------------
__global__ void k_hist(const int* __restrict__ ei, int* cnt) {
  long t = (long)blockIdx.x * 256 + threadIdx.x;
  long e0 = t * 8;
  if (e0 + 8 <= NE) {
    int4 c0 = *(const int4*)(ei + NE + e0);
    int4 c1 = *(const int4*)(ei + NE + e0 + 4);
    atomicAdd(&cnt[c0.x], 1);
    atomicAdd(&cnt[c0.y], 1);
    atomicAdd(&cnt[c0.z], 1);
    atomicAdd(&cnt[c0.w], 1);
    atomicAdd(&cnt[c1.x], 1);
    atomicAdd(&cnt[c1.y], 1);
    atomicAdd(&cnt[c1.z], 1);
    atomicAdd(&cnt[c1.w], 1);
  } else {
    for (long e = e0; e < NE; e++) atomicAdd(&cnt[ei[NE + e]], 1);
  }
}

// ---------------- exclusive scan ----------------
__global__ void k_scan1(const int* __restrict__ cnt, int* off, int* bsum) {
  __shared__ int s[1024];
  int t = threadIdx.x;
  int g = blockIdx.x * 1024 + t;
  int v = (g < NN) ? cnt[g] : 0;
  s[t] = v;
  __syncthreads();
  for (int st = 1; st < 1024; st <<= 1) {
    int x = (t >= st) ? s[t - st] : 0;
    __syncthreads();
    s[t] += x;
    __syncthreads();
  }
  if (g < NN) off[g] = s[t] - v;
  if (t == 1023) bsum[blockIdx.x] = s[t];
}

__global__ void k_scan23(int* off, const int* __restrict__ bsum, int* cur, int nb) {
  __shared__ int s[128];
  int t = threadIdx.x;
  int v = 0;
  if (t < 128) {
    v = (t < nb) ? bsum[t] : 0;
    s[t] = v;
  }
  __syncthreads();
  for (int st = 1; st < 128; st <<= 1) {
    int x = (t >= st && t < 128) ? s[t - st] : 0;
    __syncthreads();
    if (t < 128) s[t] += x;
    __syncthreads();
  }
  if (t < 128) s[t] -= v;
  __syncthreads();
  int pre = s[blockIdx.x];
  int g = blockIdx.x * 1024 + t;
  if (g < NN) {
    int o = off[g] + pre;
    off[g] = o;
    cur[g] = o;  // pre-seed CSR cursor
  }
  if (g == 0) off[NN] = NE;
}

// ---------------- CSR placement + out-degree hist; packed (row,eid) single 8B scatter ----------------
__global__ void k_place(const int* __restrict__ ei, int* cur, int* deg,
                        int2* __restrict__ cpk) {
  long t = (long)blockIdx.x * 256 + threadIdx.x;
  long e0 = t * 4;
  if (e0 + 4 <= NE) {
    int4 r4 = *(const int4*)(ei + e0);
    int4 c4 = *(const int4*)(ei + NE + e0);
    int p0 = atomicAdd(&cur[c4.x], 1);
    int p1 = atomicAdd(&cur[c4.y], 1);
    int p2 = atomicAdd(&cur[c4.z], 1);
    int p3 = atomicAdd(&cur[c4.w], 1);
    atomicAdd(&deg[r4.x], 1);
    atomicAdd(&deg[r4.y], 1);
    atomicAdd(&deg[r4.z], 1);
    atomicAdd(&deg[r4.w], 1);
    cpk[p0] = make_int2(r4.x, (int)e0);
    cpk[p1] = make_int2(r4.y, (int)e0 + 1);
    cpk[p2] = make_int2(r4.z, (int)e0 + 2);
    cpk[p3] = make_int2(r4.w, (int)e0 + 3);
  } else {
    for (long e = e0; e < NE; e++) {
      int rr = ei[e], cc = ei[NE + e];
      int p = atomicAdd(&cur[cc], 1);
      atomicAdd(&deg[rr], 1);
      cpk[p] = make_int2(rr, (int)e);
    }
  }
}

// ------------- standalone SpMM (weighted): dst = L(BN?(src)) -------------
template <int BN>
__global__ __launch_bounds__(256) void k_spmm(const u16* __restrict__ src,
                                              u16* __restrict__ dst,
                                              const int* __restrict__ off,
                                              const int2* __restrict__ cpk,
                                              const float* __restrict__ cnorm,
                                              const float* __restrict__ ab) {
  int t = threadIdx.x;
  int node = blockIdx.x * 8 + (t >> 5);
  if (node >= NN) return;
  int l = t & 31;
  int half = l >> 4;
  int c = (l & 15) * 8;
  float A[8], Bb[8];
  if (BN) {
#pragma unroll
    for (int j = 0; j < 8; j++) {
      A[j] = ab[c + j];
      Bb[j] = ab[128 + c + j];
    }
  }
  int p0 = off[node], p1 = off[node + 1];
  float a[8];
#pragma unroll
  for (int j = 0; j < 8; j++) a[j] = 0.f;
  const u16* sp = src + c;
  // masked 8-batch (4 entries per half, stride 2): full MLP incl. tails
  for (int p = p0 + half; p < p1; p += 8) {
    int rr[4];
    float w[4];
#pragma unroll
    for (int u = 0; u < 4; u++) {
      int q = p + u * 2;
      int qc = q < p1 ? q : p1 - 1;
      rr[u] = cpk[qc].x;
      w[u] = (q < p1) ? cnorm[qc] : 0.f;
    }
#pragma unroll
    for (int u = 0; u < 4; u++) {
      uint4 v = *(const uint4*)(sp + (long)rr[u] * 128);
      if (BN) acc8bn(a, v, w[u], A, Bb);
      else acc8(a, v, w[u]);
    }
  }
#pragma unroll
  for (int j = 0; j < 8; j++) a[j] += __shfl_xor(a[j], 16);
  if (half) return;
  uint4 o;
  o.x = (u32)f2bf(a[0]) | ((u32)f2bf(a[1]) << 16);
  o.y = (u32)f2bf(a[2]) | ((u32)f2bf(a[3]) << 16);
  o.z = (u32)f2bf(a[4]) | ((u32)f2bf(a[5]) << 16);
  o.w = (u32)f2bf(a[6]) | ((u32)f2bf(a[7]) << 16);
  *(uint4*)(dst + (long)node * 128 + c) = o;
}

// ------------- gather L(src) (or segsum) for 64 rows into LDS; masked 8-batch -------------
template <int WEIGHTED>
__device__ __forceinline__ void gather_lds(u16* sA, const u16* __restrict__ src,
                                           const int* __restrict__ off,
                                           const int2* __restrict__ cpk,
                                           const float* __restrict__ cnorm, int r0) {
  int tid = threadIdx.x;
  int grp = tid >> 4;      // 16 groups of 16 lanes
  int c = (tid & 15) * 8;  // 8 cols per lane
  const u16* sp = src + c;
#pragma unroll
  for (int i = 0; i < 4; i++) {
    int nl = grp * 4 + i;
    int node = r0 + nl;
    float a[8];
#pragma unroll
    for (int j = 0; j < 8; j++) a[j] = 0.f;
    if (node < NN) {
      int p0 = off[node], p1 = off[node + 1];
      for (int p = p0; p < p1; p += 8) {
        int rr[8];
        float w[8];
#pragma unroll
        for (int u = 0; u < 8; u++) {
          int q = p + u;
          int qc = q < p1 ? q : p1 - 1;
          rr[u] = cpk[qc].x;
          w[u] = (q < p1) ? (WEIGHTED ? cnorm[qc] : 1.f) : 0.f;
        }
#pragma unroll
        for (int u = 0; u < 8; u++)
          acc8(a, *(const uint4*)(sp + (long)rr[u] * 128), w[u]);
      }
    }
    uint4 o;
    o.x = (u32)f2bf(a[0]) | ((u32)f2bf(a[1]) << 16);
    o.y = (u32)f2bf(a[2]) | ((u32)f2bf(a[3]) << 16);
    o.z = (u32)f2bf(a[4]) | ((u32)f2bf(a[5]) << 16);
    o.w = (u32)f2bf(a[6]) | ((u32)f2bf(a[7]) << 16);
    *(uint4*)(sA + nl * ASTRIDE + c) = o;
  }
}

// ------------- edge_attr segment-sum ([N,16]) + cnorm (dis folded in via deg) -------------
__global__ __launch_bounds__(256) void k_asum(const void* __restrict__ eattr,
                                              const u32* __restrict__ gp,
                                              u16* __restrict__ asum,
                                              const int* __restrict__ off,
                                              const int2* __restrict__ cpk,
                                              const int* __restrict__ deg,
                                              float* __restrict__ cnorm) {
  int t = blockIdx.x * 256 + threadIdx.x;
  int node = t >> 4;
  if (node >= NN) return;
  int j = t & 15;
  int p0 = off[node], p1 = off[node + 1];
  int dn = deg[node];
  float ndis = dn > 0 ? -rsqrtf((float)dn) : 0.f;
  for (int p = p0 + j; p < p1; p += 16)
    cnorm[p] = ndis * rsqrtf((float)deg[cpk[p].x]);  // deg[crow] >= 1 by construction
  float a = 0.f;
  if (gp[0] == BF16ONE2) {
    const u16* e16 = (const u16*)eattr;
    for (int p = p0; p < p1; p += 8) {
      float s[8];
#pragma unroll
      for (int u = 0; u < 8; u++) {
        int q = p + u;
        int qc = q < p1 ? q : p1 - 1;
        float v = bf2f(e16[(long)cpk[qc].y * 16 + j]);
        s[u] = (q < p1) ? v : 0.f;
      }
      a += ((s[0] + s[1]) + (s[2] + s[3])) + ((s[4] + s[5]) + (s[6] + s[7]));
    }
  } else {
    const float* e32 = (const float*)eattr;
    for (int p = p0; p < p1; p += 8) {
      float s[8];
#pragma unroll
      for (int u = 0; u < 8; u++) {
        int q = p + u;
        int qc = q < p1 ? q : p1 - 1;
        float v = e32[(long)cpk[qc].y * 16 + j];
        s[u] = (q < p1) ? v : 0.f;
      }
      a += ((s[0] + s[1]) + (s[2] + s[3])) + ((s[4] + s[5]) + (s[6] + s[7]));
    }
  }
  asum[(long)node * 16 + j] = f2bf(a);
}

// ------------- plain MFMA GEMM (ROWS=128): out = A0@W0T^T + bias (+partials) -------------
struct MArgs {
  const void* A0; const u16* W0T; int a0raw;
  const float* bias;
  u16* out;
  const u32* gp;
  float* part;
};

__global__ __launch_bounds__(256) void k_mgemm(MArgs m) {
  constexpr int ROWS = 128, RT = 8, TPR = 2, SEGW = 64;
  __shared__ __align__(16) u16 sA[ROWS * ASTRIDE];
  int tid = threadIdx.x;
  int wv = tid >> 6, lane = tid & 63;
  int col16 = lane & 15, quad = lane >> 4;
  int r0 = blockIdx.x * ROWS;

  ffrag acc[RT * 2];
#pragma unroll
  for (int i = 0; i < RT * 2; i++)
#pragma unroll
    for (int g = 0; g < 4; g++) acc[i][g] = 0.f;

  {
    int row = tid / TPR, seg = tid % TPR;
    int ra = r0 + row;
    if (ra >= NN) ra = NN - 1;
    bool f32a = m.a0raw && (m.gp[0] != BF16ONE2);
    if (f32a) {
      const float* gs = (const float*)m.A0 + (long)ra * 128 + seg * SEGW;
      u32* lp = (u32*)(sA + row * ASTRIDE + seg * SEGW);
#pragma unroll
      for (int e = 0; e < SEGW / 8; e++) {
        float4 v0 = *(const float4*)(gs + e * 8);
        float4 v1 = *(const float4*)(gs + e * 8 + 4);
        lp[e * 4 + 0] = (u32)f2bf(v0.x) | ((u32)f2bf(v0.y) << 16);
        lp[e * 4 + 1] = (u32)f2bf(v0.z) | ((u32)f2bf(v0.w) << 16);
        lp[e * 4 + 2] = (u32)f2bf(v1.x) | ((u32)f2bf(v1.y) << 16);
        lp[e * 4 + 3] = (u32)f2bf(v1.z) | ((u32)f2bf(v1.w) << 16);
      }
    } else {
      const u16* gs = (const u16*)m.A0 + (long)ra * 128 + seg * SEGW;
      uint4* lp = (uint4*)(sA + row * ASTRIDE + seg * SEGW);
#pragma unroll
      for (int e = 0; e < SEGW / 8; e++) lp[e] = *(const uint4*)(gs + e * 8);
    }
  }
  bfrag b0[2][4];
#pragma unroll
  for (int c = 0; c < 2; c++)
#pragma unroll
    for (int kb = 0; kb < 4; kb++)
      b0[c][kb] = *(const bfrag*)(m.W0T + (long)(wv * 32 + c * 16 + col16) * 128 + kb * 32 + quad * 8);
  __syncthreads();
#pragma unroll
  for (int kb = 0; kb < 4; kb++)
#pragma unroll
    for (int rt = 0; rt < RT; rt++) {
      bfrag af = *(const bfrag*)(sA + (rt * 16 + col16) * ASTRIDE + kb * 32 + quad * 8);
      acc[rt * 2 + 0] = __builtin_amdgcn_mfma_f32_16x16x32_bf16(af, b0[0][kb], acc[rt * 2 + 0], 0, 0, 0);
      acc[rt * 2 + 1] = __builtin_amdgcn_mfma_f32_16x16x32_bf16(af, b0[1][kb], acc[rt * 2 + 1], 0, 0, 0);
    }
  __syncthreads();
#pragma unroll
  for (int rt = 0; rt < RT; rt++)
#pragma unroll
    for (int c = 0; c < 2; c++) {
      int col = wv * 32 + c * 16 + col16;
      float bj = m.bias ? m.bias[col] : 0.f;
#pragma unroll
      for (int g = 0; g < 4; g++)
        sA[(rt * 16 + quad * 4 + g) * ESTRIDE + col] = f2bf(acc[rt * 2 + c][g] + bj);
    }
  __syncthreads();
  {
    int rr = tid / TPR, d = tid % TPR;
    int rowg = r0 + rr;
    if (rowg < NN) {
      const u16* sp2 = sA + rr * ESTRIDE + d * 64;
      uint4* o = (uint4*)(m.out + (long)rowg * 128 + d * 64);
#pragma unroll
      for (int e = 0; e < 8; e++) {
        const uint2* s2 = (const uint2*)(sp2 + e * 8);
        uint2 lo = s2[0], hi = s2[1];
        o[e] = make_uint4(lo.x, lo.y, hi.x, hi.y);
      }
    }
  }
  if (m.part) {
    __shared__ float ps[256], pq[256];
    int col = tid & 127, hf = tid >> 7;
    float s = 0.f, q = 0.f;
#pragma unroll
    for (int r = 0; r < 64; r++) {
      int rr = hf * 64 + r;
      if (r0 + rr < NN) {
        float v = bf2f(sA[rr * ESTRIDE + col]);
        s += v;
        q += v * v;
      }
    }
    ps[tid] = s;
    pq[tid] = q;
    __syncthreads();
    if (tid < 128) {
      m.part[(long)blockIdx.x * 256 + tid] = ps[tid] + ps[tid + 128];
      m.part[(long)blockIdx.x * 256 + 128 + tid] = pq[tid] + pq[tid + 128];
    }
  }
}

// ------------- fused: S-gather + ET GEMM + mean + preprocess GEMM -------------
__global__ __launch_bounds__(256) void k_etpre(const u16* __restrict__ Xg,
                                               const u16* __restrict__ asum,
                                               const u16* __restrict__ Wet,
                                               const u16* __restrict__ Wpre,
                                               const float* __restrict__ b_int,
                                               const float* __restrict__ b_pre,
                                               const int* __restrict__ off,
                                               const int2* __restrict__ cpk,
                                               u16* __restrict__ out, float* part) {
  __shared__ __align__(16) u16 sA[64 * ASTRIDE];
  __shared__ __align__(16) u16 sE[64 * 32];
  int tid = threadIdx.x;
  int wv = tid >> 6, lane = tid & 63;
  int col16 = lane & 15, quad = lane >> 4;
  int r0 = blockIdx.x * 64;

  // gather S = segsum(Xg) into sA FIRST (no live accumulators during gather)
  gather_lds<0>(sA, Xg, off, cpk, nullptr, r0);
  // stage asum [64 x 16] into sE cols 0..15, zero 16..31
  {
    int row = tid >> 2, seg = tid & 3;
    int ra = r0 + row;
    if (ra >= NN) ra = NN - 1;
    if (seg < 2)
      *(uint4*)(sE + row * 32 + seg * 8) = *(const uint4*)(asum + (long)ra * 16 + seg * 8);
    else
      *(uint4*)(sE + row * 32 + seg * 8) = make_uint4(0, 0, 0, 0);
  }
  bfrag be[2];
#pragma unroll
  for (int c = 0; c < 2; c++)
    be[c] = *(const bfrag*)(Wet + (long)(wv * 32 + c * 16 + col16) * 32 + quad * 8);
  __syncthreads();
  ffrag accE[8];
#pragma unroll
  for (int i = 0; i < 8; i++)
#pragma unroll
    for (int g = 0; g < 4; g++) accE[i][g] = 0.f;
#pragma unroll
  for (int rt = 0; rt < 4; rt++) {
    bfrag af = *(const bfrag*)(sE + (rt * 16 + col16) * 32 + quad * 8);
    accE[rt * 2 + 0] = __builtin_amdgcn_mfma_f32_16x16x32_bf16(af, be[0], accE[rt * 2 + 0], 0, 0, 0);
    accE[rt * 2 + 1] = __builtin_amdgcn_mfma_f32_16x16x32_bf16(af, be[1], accE[rt * 2 + 1], 0, 0, 0);
  }
  // h = (accE + S + cnt*b)/max(cnt,1) in-place; cnt[r] = off[r+1]-off[r]
#pragma unroll
  for (int rt = 0; rt < 4; rt++)
#pragma unroll
    for (int g = 0; g < 4; g++) {
      int rr = rt * 16 + quad * 4 + g;
      int r = r0 + rr;
      int cc = (r < NN) ? off[r + 1] - off[r] : 0;
      float inv = 1.f / (float)(cc > 1 ? cc : 1);
#pragma unroll
      for (int c = 0; c < 2; c++) {
        int col = wv * 32 + c * 16 + col16;
        float bj = b_int[col];
        float v = accE[rt * 2 + c][g] + bf2f(sA[rr * ASTRIDE + col]);
        v = (v + (float)cc * bj) * inv;
        sA[rr * ASTRIDE + col] = f2bf(v);
      }
    }
  bfrag b1[2][4];
#pragma unroll
  for (int c = 0; c < 2; c++)
#pragma unroll
    for (int kb = 0; kb < 4; kb++)
      b1[c][kb] = *(const bfrag*)(Wpre + (long)(wv * 32 + c * 16 + col16) * 128 + kb * 32 + quad * 8);
  __syncthreads();
  ffrag a2[8];
#pragma unroll
  for (int i = 0; i < 8; i++)
#pragma unroll
    for (int g = 0; g < 4; g++) a2[i][g] = 0.f;
#pragma unroll
  for (int kb = 0; kb < 4; kb++)
#pragma unroll
    for (int rt = 0; rt < 4; rt++) {
      bfrag af = *(const bfrag*)(sA + (rt * 16 + col16) * ASTRIDE + kb * 32 + quad * 8);
      a2[rt * 2 + 0] = __builtin_amdgcn_mfma_f32_16x16x32_bf16(af, b1[0][kb], a2[rt * 2 + 0], 0, 0, 0);
      a2[rt * 2 + 1] = __builtin_amdgcn_mfma_f32_16x16x32_bf16(af, b1[1][kb], a2[rt * 2 + 1], 0, 0, 0);
    }
  __syncthreads();
#pragma unroll
  for (int rt = 0; rt < 4; rt++)
#pragma unroll
    for (int c = 0; c < 2; c++) {
      int col = wv * 32 + c * 16 + col16;
      float bj = b_pre[col];
#pragma unroll
      for (int g = 0; g < 4; g++)
        sA[(rt * 16 + quad * 4 + g) * ESTRIDE + col] = f2bf(a2[rt * 2 + c][g] + bj);
    }
  __syncthreads();
  {
    int rr = tid >> 2, d = tid & 3;
    int rowg = r0 + rr;
    if (rowg < NN) {
      const u16* sp2 = sA + rr * ESTRIDE + d * 32;
      uint4* o = (uint4*)(out + (long)rowg * 128 + d * 32);
#pragma unroll
      for (int e = 0; e < 4; e++) {
        const uint2* s2 = (const uint2*)(sp2 + e * 8);
        uint2 lo = s2[0], hi = s2[1];
        o[e] = make_uint4(lo.x, lo.y, hi.x, hi.y);
      }
    }
  }
  {
    __shared__ float ps[256], pq[256];
    int col = tid & 127, hf = tid >> 7;
    float s = 0.f, q = 0.f;
#pragma unroll
    for (int r = 0; r < 32; r++) {
      int rr = hf * 32 + r;
      if (r0 + rr < NN) {
        float v = bf2f(sA[rr * ESTRIDE + col]);
        s += v;
        q += v * v;
      }
    }
    ps[tid] = s;
    pq[tid] = q;
    __syncthreads();
    if (tid < 128) {
      part[(long)blockIdx.x * 256 + tid] = ps[tid] + ps[tid + 128];
      part[(long)blockIdx.x * 256 + 128 + tid] = pq[tid] + pq[tid + 128];
    }
  }
}

// ------------- fused cheb layer: out = relu(BN?(hb)@WD + T1@W1 + L(T1)@V2 + b) -------------
template <int BN>
__global__ __launch_bounds__(256) void k_cheb(const u16* __restrict__ hb,
                                              const u16* __restrict__ T1,
                                              const int* __restrict__ off,
                                              const int2* __restrict__ cpk,
                                              const float* __restrict__ cnorm,
                                              const u16* __restrict__ WD,
                                              const u16* __restrict__ W1,
                                              const u16* __restrict__ V2,
                                              const float* __restrict__ bias,
                                              const float* __restrict__ ab,
                                              u16* __restrict__ out) {
  __shared__ __align__(16) u16 sA[64 * ASTRIDE];
  int tid = threadIdx.x;
  int wv = tid >> 6, lane = tid & 63;
  int col16 = lane & 15, quad = lane >> 4;
  int r0 = blockIdx.x * 64;

  // phase 1: gather L(T1) -> sA ; MFMA with V2 (acc init deferred past gather)
  gather_lds<1>(sA, T1, off, cpk, cnorm, r0);
  bfrag bv[2][4];
#pragma unroll
  for (int c = 0; c < 2; c++)
#pragma unroll
    for (int kb = 0; kb < 4; kb++)
      bv[c][kb] = *(const bfrag*)(V2 + (long)(wv * 32 + c * 16 + col16) * 128 + kb * 32 + quad * 8);
  __syncthreads();
  ffrag acc[8];
#pragma unroll
  for (int i = 0; i < 8; i++)
#pragma unroll
    for (int g = 0; g < 4; g++) acc[i][g] = 0.f;
#pragma unroll
  for (int kb = 0; kb < 4; kb++)
#pragma unroll
    for (int rt = 0; rt < 4; rt++) {
      bfrag af = *(const bfrag*)(sA + (rt * 16 + col16) * ASTRIDE + kb * 32 + quad * 8);
      acc[rt * 2 + 0] = __builtin_amdgcn_mfma_f32_16x16x32_bf16(af, bv[0][kb], acc[rt * 2 + 0], 0, 0, 0);
      acc[rt * 2 + 1] = __builtin_amdgcn_mfma_f32_16x16x32_bf16(af, bv[1][kb], acc[rt * 2 + 1], 0, 0, 0);
    }
  __syncthreads();

  // phase 2: stage hb own rows (BN+ReLU fused when BN=1) ; MFMA with WD
  {
    int row = tid >> 2, seg = tid & 3;
    int ra = r0 + row;
    if (ra >= NN) ra = NN - 1;
    const u16* gs = hb + (long)ra * 128 + seg * 32;
    uint4* lp = (uint4*)(sA + row * ASTRIDE + seg * 32);
    if (BN) {
#pragma unroll
      for (int e = 0; e < 4; e++) {
        uint4 v = *(const uint4*)(gs + e * 8);
        int cb = seg * 32 + e * 8;
        float f0 = fmaxf(fmaf(ab[cb + 0], __uint_as_float(v.x << 16), ab[128 + cb + 0]), 0.f);
        float f1 = fmaxf(fmaf(ab[cb + 1], __uint_as_float(v.x & 0xffff0000u), ab[128 + cb + 1]), 0.f);
        float f2 = fmaxf(fmaf(ab[cb + 2], __uint_as_float(v.y << 16), ab[128 + cb + 2]), 0.f);
        float f3 = fmaxf(fmaf(ab[cb + 3], __uint_as_float(v.y & 0xffff0000u), ab[128 + cb + 3]), 0.f);
        float f4 = fmaxf(fmaf(ab[cb + 4], __uint_as_float(v.z << 16), ab[128 + cb + 4]), 0.f);
        float f5 = fmaxf(fmaf(ab[cb + 5], __uint_as_float(v.z & 0xffff0000u), ab[128 + cb + 5]), 0.f);
        float f6 = fmaxf(fmaf(ab[cb + 6], __uint_as_float(v.w << 16), ab[128 + cb + 6]), 0.f);
        float f7 = fmaxf(fmaf(ab[cb + 7], __uint_as_float(v.w & 0xffff0000u), ab[128 + cb + 7]), 0.f);
        uint4 o;
        o.x = (u32)f2bf(f0) | ((u32)f2bf(f1) << 16);
        o.y = (u32)f2bf(f2) | ((u32)f2bf(f3) << 16);
        o.z = (u32)f2bf(f4) | ((u32)f2bf(f5) << 16);
        o.w = (u32)f2bf(f6) | ((u32)f2bf(f7) << 16);
        lp[e] = o;
      }
    } else {
#pragma unroll
      for (int e = 0; e < 4; e++) lp[e] = *(const uint4*)(gs + e * 8);
    }
  }
#pragma unroll
  for (int c = 0; c < 2; c++)
#pragma unroll
    for (int kb = 0; kb < 4; kb++)
      bv[c][kb] = *(const bfrag*)(WD + (long)(wv * 32 + c * 16 + col16) * 128 + kb * 32 + quad * 8);
  __syncthreads();
#pragma unroll
  for (int kb = 0; kb < 4; kb++)
#pragma unroll
    for (int rt = 0; rt < 4; rt++) {
      bfrag af = *(const bfrag*)(sA + (rt * 16 + col16) * ASTRIDE + kb * 32 + quad * 8);
      acc[rt * 2 + 0] = __builtin_amdgcn_mfma_f32_16x16x32_bf16(af, bv[0][kb], acc[rt * 2 + 0], 0, 0, 0);
      acc[rt * 2 + 1] = __builtin_amdgcn_mfma_f32_16x16x32_bf16(af, bv[1][kb], acc[rt * 2 + 1], 0, 0, 0);
    }
  __syncthreads();

  // phase 3: stage T1 own rows ; MFMA with W1
  {
    int row = tid >> 2, seg = tid & 3;
    int ra = r0 + row;
    if (ra >= NN) ra = NN - 1;
    const u16* gs = T1 + (long)ra * 128 + seg * 32;
    uint4* lp = (uint4*)(sA + row * ASTRIDE + seg * 32);
#pragma unroll
    for (int e = 0; e < 4; e++) lp[e] = *(const uint4*)(gs + e * 8);
  }
#pragma unroll
  for (int c = 0; c < 2; c++)
#pragma unroll
    for (int kb = 0; kb < 4; kb++)
      bv[c][kb] = *(const bfrag*)(W1 + (long)(wv * 32 + c * 16 + col16) * 128 + kb * 32 + quad * 8);
  __syncthreads();
#pragma unroll
  for (int kb = 0; kb < 4; kb++)
#pragma unroll
    for (int rt = 0; rt < 4; rt++) {
      bfrag af = *(const bfrag*)(sA + (rt * 16 + col16) * ASTRIDE + kb * 32 + quad * 8);
      acc[rt * 2 + 0] = __builtin_amdgcn_mfma_f32_16x16x32_bf16(af, bv[0][kb], acc[rt * 2 + 0], 0, 0, 0);
      acc[rt * 2 + 1] = __builtin_amdgcn_mfma_f32_16x16x32_bf16(af, bv[1][kb], acc[rt * 2 + 1], 0, 0, 0);
    }
  __syncthreads();

  // epilogue: +bias, relu, repack, store
#pragma unroll
  for (int rt = 0; rt < 4; rt++)
#pragma unroll
    for (int c = 0; c < 2; c++) {
      int col = wv * 32 + c * 16 + col16;
      float bj = bias[col];
#pragma unroll
      for (int g = 0; g < 4; g++)
        sA[(rt * 16 + quad * 4 + g) * ESTRIDE + col] = f2bf(fmaxf(acc[rt * 2 + c][g] + bj, 0.f));
    }
  __syncthreads();
  {
    int rr = tid >> 2, d = tid & 3;
    int rowg = r0 + rr;
    if (rowg < NN) {
      const u16* sp2 = sA + rr * ESTRIDE + d * 32;
      uint4* o = (uint4*)(out + (long)rowg * 128 + d * 32);
#pragma unroll
      for (int e = 0; e < 4; e++) {
        const uint2* s2 = (const uint2*)(sp2 + e * 8);
        uint2 lo = s2[0], hi = s2[1];
        o[e] = make_uint4(lo.x, lo.y, hi.x, hi.y);
      }
    }
  }
}

// ------------- reduce partials + BN finalize fused -------------
__global__ void k_redfin(const float* __restrict__ part, const float* __restrict__ gamma,
                         const float* __restrict__ beta, float* ab, int nblk) {
  int tid = threadIdx.x;
  int col = blockIdx.x * 16 + (tid & 15);
  int ch = tid >> 4;
  float s = 0.f, q = 0.f;
  for (int b = ch; b < nblk; b += 16) {
    s += part[(long)b * 256 + col];
    q += part[(long)b * 256 + 128 + col];
  }
  __shared__ float sh[256], qh[256];
  sh[tid] = s;
  qh[tid] = q;
  __syncthreads();
  if (tid < 16) {
    float ts = 0.f, tq = 0.f;
#pragma unroll
    for (int i = 0; i < 16; i++) {
      ts += sh[i * 16 + tid];
      tq += qh[i * 16 + tid];
    }
    int j = blockIdx.x * 16 + tid;
    float m = ts * (1.f / (float)NN);
    float v = fmaxf(tq * (1.f / (float)NN) - m * m, 0.f);
    float a = gamma[j] * rsqrtf(v + 1e-5f);
    ab[j] = a;
    ab[128 + j] = beta[j] - m * a;
  }
}

__global__ void k_out(const u16* __restrict__ z, const float* __restrict__ ab,
                      const float* __restrict__ wout, const float* __restrict__ bout,
                      const u32* __restrict__ gp, void* __restrict__ y) {
  int node = blockIdx.x * 4 + (threadIdx.x >> 6);
  if (node >= NN) return;
  int lane = threadIdx.x & 63;
  float s = 0.f;
#pragma unroll
  for (int c = lane; c < 128; c += 64) {
    float zz = bf2f(z[(long)node * 128 + c]);
    float h = fmaxf(ab[c] * zz + ab[128 + c], 0.f);
    s += h * wout[c];
  }
#pragma unroll
  for (int o = 32; o > 0; o >>= 1) s += __shfl_down(s, o);
  if (lane == 0) {
    float r = s + bout[0];
    if (gp[0] == BF16ONE2) ((u16*)y)[node] = f2bf(r);
    else ((float*)y)[node] = r;
  }
}

extern "C" void kernel_launch(void* const* d_in, const int* in_sizes, int n_in,
                              void* d_out, int out_size, void* d_ws, size_t ws_size,
                              hipStream_t stream) {
  const void* x = d_in[0];
  const int* ei = (const int*)d_in[1];
  const void* eattr = d_in[2];
  const u32* gp = (const u32*)d_in[7];
  (void)in_sizes; (void)n_in; (void)out_size; (void)ws_size;

  char* w = (char*)d_ws;
  size_t p = 0;
  auto alloc = [&](size_t b) { size_t r = p; p += (b + 255) & ~(size_t)255; return r; };
  size_t o_cnt = alloc((size_t)NN * 4);
  size_t o_deg = alloc((size_t)NN * 4);
  size_t o_zero_end = p;
  size_t o_cur = alloc((size_t)NN * 4);
  size_t o_off = alloc((size_t)(NN + 1) * 4);
  size_t o_bsum = alloc(1024 * 4);
  size_t o_ab = alloc(512 * 4);
  size_t o_wq = alloc((size_t)151552 * 2);
  size_t o_wf = alloc((size_t)1281 * 4);
  size_t o_cpk = alloc((size_t)NE * 8);
  size_t o_cnrm = alloc((size_t)NE * 4);
  size_t o_asum = alloc((size_t)NN * 16 * 2);
  size_t o_part = alloc((size_t)1563 * 256 * 4);
  size_t o_Bx = alloc((size_t)NN * 128 * 2);
  size_t o_Bt = alloc((size_t)NN * 128 * 2);

  int* cnt = (int*)(w + o_cnt);
  int* deg = (int*)(w + o_deg);
  int* cur = (int*)(w + o_cur);
  int* off = (int*)(w + o_off);
  int* bsum = (int*)(w + o_bsum);
  float* abA = (float*)(w + o_ab);
  float* abB = abA + 256;
  u16* wq = (u16*)(w + o_wq);
  float* wf = (float*)(w + o_wf);
  int2* cpk = (int2*)(w + o_cpk);
  float* cnrm = (float*)(w + o_cnrm);
  u16* asum = (u16*)(w + o_asum);
  float* part = (float*)(w + o_part);
  u16* Bx = (u16*)(w + o_Bx);
  u16* Bt = (u16*)(w + o_Bt);

  hipMemsetAsync(w + o_cnt, 0, o_zero_end - o_cnt, stream);  // zero cnt+deg

  int gH = (NE / 8 + 255) / 256;  // 489: 8 edges/thread (hist)
  int gP = (NE / 4 + 255) / 256;  // 977: 4 edges/thread (place)
  int nb = (NN + 1023) / 1024;
  int gS = (NN + 7) / 8;
  int gG1 = (NN + 127) / 128;  // 782
  int gG2 = (NN + 63) / 64;    // 1563

  {
    PrepArgs a;
    for (int i = 0; i < 16; i++) a.in[i] = d_in[3 + i];
    k_prep<<<64, 256, 0, stream>>>(a, gp, wq, wf);
  }

  k_hist<<<gH, 256, 0, stream>>>(ei, cnt);
  k_scan1<<<nb, 1024, 0, stream>>>(cnt, off, bsum);
  k_scan23<<<nb, 1024, 0, stream>>>(off, bsum, cur, nb);
  k_place<<<gP, 256, 0, stream>>>(ei, cur, deg, cpk);
  k_asum<<<(NN * 16 + 255) / 256, 256, 0, stream>>>(eattr, gp, asum, off, cpk, deg, cnrm);

  // ---- Xg = x @ Wx -> Bx
  {
    MArgs a = {};
    a.A0 = x; a.W0T = wq + OWXT; a.a0raw = 1;
    a.out = Bx; a.gp = gp;
    k_mgemm<<<gG1, 256, 0, stream>>>(a);
  }
  // ---- fused: S = segsum(Xg), h = (S+asum@We+cnt*b)/cnt, z = h@Wpre+b -> Bt
  k_etpre<<<gG2, 256, 0, stream>>>(Bx, asum, wq + OWET, wq + OWPRE, wf + 0, wf + 128,
                                   off, cpk, Bt, part);
  k_redfin<<<8, 256, 0, stream>>>(part, wf + 256, wf + 384, abA, gG2);

  // ---- cheb1 (BN fused into consumers; hb never materialized)
  // T1 = L(relu(bn(z))): Bt -> Bx
  k_spmm<1><<<gS, 256, 0, stream>>>(Bt, Bx, off, cpk, cnrm, abA);
  // h2 = relu(bn(z)@WD1 + T1@W11 + L(T1)@V21 + b): (Bt,Bx) -> Bt (own-rows in-place safe)
  k_cheb<1><<<gG2, 256, 0, stream>>>(Bt, Bx, off, cpk, cnrm,
                                     wq + OWD1, wq + OW11, wq + OV21, wf + 512, abA, Bt);

  // ---- cheb2 (plain)
  k_spmm<0><<<gS, 256, 0, stream>>>(Bt, Bx, off, cpk, cnrm, nullptr);
  k_cheb<0><<<gG2, 256, 0, stream>>>(Bt, Bx, off, cpk, cnrm,
                                     wq + OWD2, wq + OW12, wq + OV22, wf + 640, nullptr, Bt);

  // ---- postprocess: z2 = h3@Wpost + b -> Bx (+partials) ; BN+relu+dot -> y
  {
    MArgs a = {};
    a.A0 = Bt; a.W0T = wq + OWPOST;
    a.bias = wf + 768; a.out = Bx; a.gp = gp; a.part = part;
    k_mgemm<<<gG1, 256, 0, stream>>>(a);
  }
  k_redfin<<<8, 256, 0, stream>>>(part, wf + 896, wf + 1024, abB, gG1);
  k_out<<<(NN + 3) / 4, 256, 0, stream>>>(Bx, abB, wf + 1152, wf + 1280, gp, d_out);
}

// Round 5
// 671.083 us; speedup vs baseline: 1.1425x; 1.1018x over previous
//
#include <hip/hip_runtime.h>
#include <hip/hip_bf16.h>

using u16 = unsigned short;
using u32 = unsigned int;

#define NN 100000
#define NE 1000000
#define NBKT 196   // col/row buckets: (NN-1)>>9 = 195
#define NBLK 489   // ceil(NE/2048)

typedef __attribute__((ext_vector_type(8))) short bfrag;
typedef __attribute__((ext_vector_type(4))) float ffrag;

#define BF16ONE2 0x3F803F80u

__device__ __forceinline__ float bf2f(u16 u) { return __uint_as_float(((u32)u) << 16); }
__device__ __forceinline__ u16 f2bf(float f) {
  u32 x = __float_as_uint(f);
  return (u16)((x + 0x7fffu + ((x >> 16) & 1u)) >> 16);
}
__device__ __forceinline__ float rdv(const void* p, long i, int f) {
  return f ? bf2f(((const u16*)p)[i]) : ((const float*)p)[i];
}
__device__ __forceinline__ void acc8(float* a, uint4 v, float w) {
  a[0] = fmaf(w, __uint_as_float(v.x << 16), a[0]);
  a[1] = fmaf(w, __uint_as_float(v.x & 0xffff0000u), a[1]);
  a[2] = fmaf(w, __uint_as_float(v.y << 16), a[2]);
  a[3] = fmaf(w, __uint_as_float(v.y & 0xffff0000u), a[3]);
  a[4] = fmaf(w, __uint_as_float(v.z << 16), a[4]);
  a[5] = fmaf(w, __uint_as_float(v.z & 0xffff0000u), a[5]);
  a[6] = fmaf(w, __uint_as_float(v.w << 16), a[6]);
  a[7] = fmaf(w, __uint_as_float(v.w & 0xffff0000u), a[7]);
}
// BN+ReLU applied to source value before weighted accumulate
__device__ __forceinline__ void acc8bn(float* a, uint4 v, float w, const float* A,
                                       const float* Bb) {
  float x;
  x = __uint_as_float(v.x << 16);
  a[0] = fmaf(w, fmaxf(fmaf(A[0], x, Bb[0]), 0.f), a[0]);
  x = __uint_as_float(v.x & 0xffff0000u);
  a[1] = fmaf(w, fmaxf(fmaf(A[1], x, Bb[1]), 0.f), a[1]);
  x = __uint_as_float(v.y << 16);
  a[2] = fmaf(w, fmaxf(fmaf(A[2], x, Bb[2]), 0.f), a[2]);
  x = __uint_as_float(v.y & 0xffff0000u);
  a[3] = fmaf(w, fmaxf(fmaf(A[3], x, Bb[3]), 0.f), a[3]);
  x = __uint_as_float(v.z << 16);
  a[4] = fmaf(w, fmaxf(fmaf(A[4], x, Bb[4]), 0.f), a[4]);
  x = __uint_as_float(v.z & 0xffff0000u);
  a[5] = fmaf(w, fmaxf(fmaf(A[5], x, Bb[5]), 0.f), a[5]);
  x = __uint_as_float(v.w << 16);
  a[6] = fmaf(w, fmaxf(fmaf(A[6], x, Bb[6]), 0.f), a[6]);
  x = __uint_as_float(v.w & 0xffff0000u);
  a[7] = fmaf(w, fmaxf(fmaf(A[7], x, Bb[7]), 0.f), a[7]);
}

// wq (u16) element offsets
#define OWXT 0
#define OWPRE 16384
#define OWD1 32768
#define OW11 49152
#define OV21 65536
#define OWD2 81920
#define OW12 98304
#define OV22 114688
#define OWPOST 131072
#define OWET 147456

#define ASTRIDE 136
#define ESTRIDE 132

struct PrepArgs { const void* in[16]; };

__global__ void k_prep(PrepArgs a, const u32* __restrict__ gp, u16* __restrict__ wq,
                       float* __restrict__ wf) {
  int t = blockIdx.x * 256 + threadIdx.x;
  int f = (gp[0] == BF16ONE2) ? 1 : 0;
  if (t < 16384) {
    int o = t >> 7, k = t & 127;
    int ko = k * 128 + o;
    int ok = o * 128 + k;
    wq[OWXT + ok] = f2bf(rdv(a.in[0], ko, f));
    wq[OWPRE + ok] = f2bf(rdv(a.in[2], ko, f));
    float c0 = rdv(a.in[6], ko, f);
    float c1 = rdv(a.in[6], 16384 + ko, f);
    float c2 = rdv(a.in[6], 32768 + ko, f);
    wq[OWD1 + ok] = f2bf(c0 - c2);
    wq[OW11 + ok] = f2bf(c1);
    wq[OV21 + ok] = f2bf(2.f * c2);
    float d0 = rdv(a.in[8], ko, f);
    float d1 = rdv(a.in[8], 16384 + ko, f);
    float d2 = rdv(a.in[8], 32768 + ko, f);
    wq[OWD2 + ok] = f2bf(d0 - d2);
    wq[OW12 + ok] = f2bf(d1);
    wq[OV22 + ok] = f2bf(2.f * d2);
    wq[OWPOST + ok] = f2bf(rdv(a.in[10], ko, f));
  }
  if (t < 4096) {
    int o = t >> 5, k = t & 31;
    wq[OWET + o * 32 + k] = (k < 16) ? f2bf(rdv(a.in[0], (long)(128 + k) * 128 + o, f)) : (u16)0;
  }
  if (t < 1281) {
    int s = t >> 7, j = t & 127;
    const int map[11] = {1, 3, 4, 5, 7, 9, 11, 12, 13, 14, 15};
    wf[t] = rdv(a.in[map[s]], j, f);
  }
}

// ======== CSR build via LDS two-level counting sort (zero global atomics) ========

// per-block bucket counts for cols (bcnt) and rows (rbcnt); layout [bucket][block]
__global__ void k_cnt(const int* __restrict__ ei, int* __restrict__ bcnt,
                      int* __restrict__ rbcnt) {
  __shared__ int hc[NBKT], hr[NBKT];
  int t = threadIdx.x, blk = blockIdx.x;
  for (int i = t; i < NBKT; i += 256) { hc[i] = 0; hr[i] = 0; }
  __syncthreads();
  long base = (long)blk * 2048;
#pragma unroll
  for (int i = 0; i < 8; i++) {
    long e = base + i * 256 + t;
    if (e < NE) {
      atomicAdd(&hc[ei[NE + e] >> 9], 1);
      atomicAdd(&hr[ei[e] >> 9], 1);
    }
  }
  __syncthreads();
  for (int i = t; i < NBKT; i += 256) {
    bcnt[i * NBLK + blk] = hc[i];
    rbcnt[i * NBLK + blk] = hr[i];
  }
}

// in-place exclusive scan of each bucket row (489 entries); totals -> btot[392]
__global__ void k_bscan(int* __restrict__ bcnt, int* __restrict__ rbcnt,
                        int* __restrict__ btot) {
  __shared__ int ss[256];
  int j = blockIdx.x, t = threadIdx.x;
  int* arr = ((j < NBKT) ? bcnt : rbcnt) + (j % NBKT) * NBLK;
  int a = (2 * t < NBLK) ? arr[2 * t] : 0;
  int b = (2 * t + 1 < NBLK) ? arr[2 * t + 1] : 0;
  ss[t] = a + b;
  __syncthreads();
  for (int st = 1; st < 256; st <<= 1) {
    int x = (t >= st) ? ss[t - st] : 0;
    __syncthreads();
    ss[t] += x;
    __syncthreads();
  }
  int base = ss[t] - a - b;
  if (2 * t < NBLK) arr[2 * t] = base;
  if (2 * t + 1 < NBLK) arr[2 * t + 1] = base + a;
  if (t == 255) btot[j] = ss[255];
}

// bucket bases (exclusive scan of 196 totals, twice) + off[NN]=NE
__global__ void k_bbase(const int* __restrict__ btot, int* __restrict__ bbase,
                        int* __restrict__ rbbase, int* __restrict__ off) {
  __shared__ int ss[256];
  int t = threadIdx.x;
  int v = (t < NBKT) ? btot[t] : 0;
  ss[t] = v;
  __syncthreads();
  for (int st = 1; st < 256; st <<= 1) {
    int x = (t >= st) ? ss[t - st] : 0;
    __syncthreads();
    ss[t] += x;
    __syncthreads();
  }
  if (t < NBKT) bbase[t] = ss[t] - v;
  if (t == NBKT - 1) bbase[NBKT] = ss[t];
  __syncthreads();
  int v2 = (t < NBKT) ? btot[NBKT + t] : 0;
  ss[t] = v2;
  __syncthreads();
  for (int st = 1; st < 256; st <<= 1) {
    int x = (t >= st) ? ss[t - st] : 0;
    __syncthreads();
    ss[t] += x;
    __syncthreads();
  }
  if (t < NBKT) rbbase[t] = ss[t] - v2;
  if (t == NBKT - 1) rbbase[NBKT] = ss[t];
  if (t == 0) off[NN] = NE;
}

// coarse scatter into bucket regions: sle=(low9<<20)|eid20, srow=row, srl=row&511
__global__ void k_scat(const int* __restrict__ ei, const int* __restrict__ bofs,
                       const int* __restrict__ rbofs, const int* __restrict__ bbase,
                       const int* __restrict__ rbbase, u32* __restrict__ sle,
                       u32* __restrict__ srow, u16* __restrict__ srl) {
  __shared__ int cc[NBKT], cr[NBKT], cbase[NBKT], rbase[NBKT];
  int t = threadIdx.x, blk = blockIdx.x;
  for (int i = t; i < NBKT; i += 256) {
    cc[i] = 0;
    cr[i] = 0;
    cbase[i] = bbase[i] + bofs[i * NBLK + blk];
    rbase[i] = rbbase[i] + rbofs[i * NBLK + blk];
  }
  __syncthreads();
  long base = (long)blk * 2048;
#pragma unroll
  for (int i = 0; i < 8; i++) {
    long e = base + i * 256 + t;
    if (e < NE) {
      int c = ei[NE + e], r = ei[e];
      int k1 = atomicAdd(&cc[c >> 9], 1);
      int d1 = cbase[c >> 9] + k1;
      sle[d1] = ((u32)(c & 511) << 20) | (u32)e;
      srow[d1] = (u32)r;
      int k2 = atomicAdd(&cr[r >> 9], 1);
      int d2 = rbase[r >> 9] + k2;
      srl[d2] = (u16)(r & 511);
    }
  }
}

// fine counting sort within each col bucket: writes off[] and final cpk[]
__global__ void k_fine(const u32* __restrict__ sle, const u32* __restrict__ srow,
                       const int* __restrict__ bbase, int* __restrict__ off,
                       int2* __restrict__ cpk) {
  __shared__ u32 hist[512];
  __shared__ u32 ss[256];
  int t = threadIdx.x, b = blockIdx.x;
  hist[t] = 0;
  hist[t + 256] = 0;
  __syncthreads();
  int lo = bbase[b], hi = bbase[b + 1];
  for (int p = lo + t; p < hi; p += 256) atomicAdd(&hist[sle[p] >> 20], 1);
  __syncthreads();
  u32 a = hist[2 * t], bb = hist[2 * t + 1];
  ss[t] = a + bb;
  __syncthreads();
  for (int st = 1; st < 256; st <<= 1) {
    u32 x = (t >= st) ? ss[t - st] : 0;
    __syncthreads();
    ss[t] += x;
    __syncthreads();
  }
  u32 base = ss[t] - a - bb;
  u32 c0 = (u32)lo + base, c1 = (u32)lo + base + a;
  hist[2 * t] = c0;
  hist[2 * t + 1] = c1;
  int col0 = b * 512 + 2 * t, col1 = col0 + 1;
  if (col0 < NN) off[col0] = (int)c0;
  if (col1 < NN) off[col1] = (int)c1;
  __syncthreads();
  for (int p = lo + t; p < hi; p += 256) {
    u32 v = sle[p];
    u32 pos = atomicAdd(&hist[v >> 20], 1);
    cpk[pos] = make_int2((int)srow[p], (int)(v & 0xFFFFFu));
  }
}

// out-degree per node from row-staged low bits (no atomics to global)
__global__ void k_deg(const u16* __restrict__ srl, const int* __restrict__ rbbase,
                      int* __restrict__ deg) {
  __shared__ int hist[512];
  int t = threadIdx.x, b = blockIdx.x;
  hist[t] = 0;
  hist[t + 256] = 0;
  __syncthreads();
  int lo = rbbase[b], hi = rbbase[b + 1];
  for (int p = lo + t; p < hi; p += 256) atomicAdd(&hist[srl[p]], 1);
  __syncthreads();
  int n0 = b * 512 + t, n1 = n0 + 256;
  if (n0 < NN) deg[n0] = hist[t];
  if (n1 < NN) deg[n1] = hist[t + 256];
}

// ------------- standalone SpMM (weighted): dst = L(BN?(src)) -------------
template <int BN>
__global__ __launch_bounds__(256) void k_spmm(const u16* __restrict__ src,
                                              u16* __restrict__ dst,
                                              const int* __restrict__ off,
                                              const int2* __restrict__ cpk,
                                              const float* __restrict__ cnorm,
                                              const float* __restrict__ ab) {
  int t = threadIdx.x;
  int node = blockIdx.x * 8 + (t >> 5);
  if (node >= NN) return;
  int l = t & 31;
  int half = l >> 4;
  int c = (l & 15) * 8;
  float A[8], Bb[8];
  if (BN) {
#pragma unroll
    for (int j = 0; j < 8; j++) {
      A[j] = ab[c + j];
      Bb[j] = ab[128 + c + j];
    }
  }
  int p0 = off[node], p1 = off[node + 1];
  float a[8];
#pragma unroll
  for (int j = 0; j < 8; j++) a[j] = 0.f;
  const u16* sp = src + c;
  // masked 8-batch (4 entries per half, stride 2): full MLP incl. tails
  for (int p = p0 + half; p < p1; p += 8) {
    int rr[4];
    float w[4];
#pragma unroll
    for (int u = 0; u < 4; u++) {
      int q = p + u * 2;
      int qc = q < p1 ? q : p1 - 1;
      rr[u] = cpk[qc].x;
      w[u] = (q < p1) ? cnorm[qc] : 0.f;
    }
#pragma unroll
    for (int u = 0; u < 4; u++) {
      uint4 v = *(const uint4*)(sp + (long)rr[u] * 128);
      if (BN) acc8bn(a, v, w[u], A, Bb);
      else acc8(a, v, w[u]);
    }
  }
#pragma unroll
  for (int j = 0; j < 8; j++) a[j] += __shfl_xor(a[j], 16);
  if (half) return;
  uint4 o;
  o.x = (u32)f2bf(a[0]) | ((u32)f2bf(a[1]) << 16);
  o.y = (u32)f2bf(a[2]) | ((u32)f2bf(a[3]) << 16);
  o.z = (u32)f2bf(a[4]) | ((u32)f2bf(a[5]) << 16);
  o.w = (u32)f2bf(a[6]) | ((u32)f2bf(a[7]) << 16);
  *(uint4*)(dst + (long)node * 128 + c) = o;
}

// ------------- gather L(src) (or segsum) for 64 rows into LDS; masked 8-batch -------------
template <int WEIGHTED>
__device__ __forceinline__ void gather_lds(u16* sA, const u16* __restrict__ src,
                                           const int* __restrict__ off,
                                           const int2* __restrict__ cpk,
                                           const float* __restrict__ cnorm, int r0) {
  int tid = threadIdx.x;
  int grp = tid >> 4;      // 16 groups of 16 lanes
  int c = (tid & 15) * 8;  // 8 cols per lane
  const u16* sp = src + c;
#pragma unroll
  for (int i = 0; i < 4; i++) {
    int nl = grp * 4 + i;
    int node = r0 + nl;
    float a[8];
#pragma unroll
    for (int j = 0; j < 8; j++) a[j] = 0.f;
    if (node < NN) {
      int p0 = off[node], p1 = off[node + 1];
      for (int p = p0; p < p1; p += 8) {
        int rr[8];
        float w[8];
#pragma unroll
        for (int u = 0; u < 8; u++) {
          int q = p + u;
          int qc = q < p1 ? q : p1 - 1;
          rr[u] = cpk[qc].x;
          w[u] = (q < p1) ? (WEIGHTED ? cnorm[qc] : 1.f) : 0.f;
        }
#pragma unroll
        for (int u = 0; u < 8; u++)
          acc8(a, *(const uint4*)(sp + (long)rr[u] * 128), w[u]);
      }
    }
    uint4 o;
    o.x = (u32)f2bf(a[0]) | ((u32)f2bf(a[1]) << 16);
    o.y = (u32)f2bf(a[2]) | ((u32)f2bf(a[3]) << 16);
    o.z = (u32)f2bf(a[4]) | ((u32)f2bf(a[5]) << 16);
    o.w = (u32)f2bf(a[6]) | ((u32)f2bf(a[7]) << 16);
    *(uint4*)(sA + nl * ASTRIDE + c) = o;
  }
}

// ------------- edge_attr segment-sum ([N,16]) + cnorm (dis folded in via deg) -------------
__global__ __launch_bounds__(256) void k_asum(const void* __restrict__ eattr,
                                              const u32* __restrict__ gp,
                                              u16* __restrict__ asum,
                                              const int* __restrict__ off,
                                              const int2* __restrict__ cpk,
                                              const int* __restrict__ deg,
                                              float* __restrict__ cnorm) {
  int t = blockIdx.x * 256 + threadIdx.x;
  int node = t >> 4;
  if (node >= NN) return;
  int j = t & 15;
  int p0 = off[node], p1 = off[node + 1];
  int dn = deg[node];
  float ndis = dn > 0 ? -rsqrtf((float)dn) : 0.f;
  for (int p = p0 + j; p < p1; p += 16)
    cnorm[p] = ndis * rsqrtf((float)deg[cpk[p].x]);  // deg[crow] >= 1 by construction
  float a = 0.f;
  if (gp[0] == BF16ONE2) {
    const u16* e16 = (const u16*)eattr;
    for (int p = p0; p < p1; p += 8) {
      float s[8];
#pragma unroll
      for (int u = 0; u < 8; u++) {
        int q = p + u;
        int qc = q < p1 ? q : p1 - 1;
        float v = bf2f(e16[(long)cpk[qc].y * 16 + j]);
        s[u] = (q < p1) ? v : 0.f;
      }
      a += ((s[0] + s[1]) + (s[2] + s[3])) + ((s[4] + s[5]) + (s[6] + s[7]));
    }
  } else {
    const float* e32 = (const float*)eattr;
    for (int p = p0; p < p1; p += 8) {
      float s[8];
#pragma unroll
      for (int u = 0; u < 8; u++) {
        int q = p + u;
        int qc = q < p1 ? q : p1 - 1;
        float v = e32[(long)cpk[qc].y * 16 + j];
        s[u] = (q < p1) ? v : 0.f;
      }
      a += ((s[0] + s[1]) + (s[2] + s[3])) + ((s[4] + s[5]) + (s[6] + s[7]));
    }
  }
  asum[(long)node * 16 + j] = f2bf(a);
}

// ------------- plain MFMA GEMM (ROWS=128): out = A0@W0T^T + bias (+partials) -------------
struct MArgs {
  const void* A0; const u16* W0T; int a0raw;
  const float* bias;
  u16* out;
  const u32* gp;
  float* part;
};

__global__ __launch_bounds__(256) void k_mgemm(MArgs m) {
  constexpr int ROWS = 128, RT = 8, TPR = 2, SEGW = 64;
  __shared__ __align__(16) u16 sA[ROWS * ASTRIDE];
  int tid = threadIdx.x;
  int wv = tid >> 6, lane = tid & 63;
  int col16 = lane & 15, quad = lane >> 4;
  int r0 = blockIdx.x * ROWS;

  ffrag acc[RT * 2];
#pragma unroll
  for (int i = 0; i < RT * 2; i++)
#pragma unroll
    for (int g = 0; g < 4; g++) acc[i][g] = 0.f;

  {
    int row = tid / TPR, seg = tid % TPR;
    int ra = r0 + row;
    if (ra >= NN) ra = NN - 1;
    bool f32a = m.a0raw && (m.gp[0] != BF16ONE2);
    if (f32a) {
      const float* gs = (const float*)m.A0 + (long)ra * 128 + seg * SEGW;
      u32* lp = (u32*)(sA + row * ASTRIDE + seg * SEGW);
#pragma unroll
      for (int e = 0; e < SEGW / 8; e++) {
        float4 v0 = *(const float4*)(gs + e * 8);
        float4 v1 = *(const float4*)(gs + e * 8 + 4);
        lp[e * 4 + 0] = (u32)f2bf(v0.x) | ((u32)f2bf(v0.y) << 16);
        lp[e * 4 + 1] = (u32)f2bf(v0.z) | ((u32)f2bf(v0.w) << 16);
        lp[e * 4 + 2] = (u32)f2bf(v1.x) | ((u32)f2bf(v1.y) << 16);
        lp[e * 4 + 3] = (u32)f2bf(v1.z) | ((u32)f2bf(v1.w) << 16);
      }
    } else {
      const u16* gs = (const u16*)m.A0 + (long)ra * 128 + seg * SEGW;
      uint4* lp = (uint4*)(sA + row * ASTRIDE + seg * SEGW);
#pragma unroll
      for (int e = 0; e < SEGW / 8; e++) lp[e] = *(const uint4*)(gs + e * 8);
    }
  }
  bfrag b0[2][4];
#pragma unroll
  for (int c = 0; c < 2; c++)
#pragma unroll
    for (int kb = 0; kb < 4; kb++)
      b0[c][kb] = *(const bfrag*)(m.W0T + (long)(wv * 32 + c * 16 + col16) * 128 + kb * 32 + quad * 8);
  __syncthreads();
#pragma unroll
  for (int kb = 0; kb < 4; kb++)
#pragma unroll
    for (int rt = 0; rt < RT; rt++) {
      bfrag af = *(const bfrag*)(sA + (rt * 16 + col16) * ASTRIDE + kb * 32 + quad * 8);
      acc[rt * 2 + 0] = __builtin_amdgcn_mfma_f32_16x16x32_bf16(af, b0[0][kb], acc[rt * 2 + 0], 0, 0, 0);
      acc[rt * 2 + 1] = __builtin_amdgcn_mfma_f32_16x16x32_bf16(af, b0[1][kb], acc[rt * 2 + 1], 0, 0, 0);
    }
  __syncthreads();
#pragma unroll
  for (int rt = 0; rt < RT; rt++)
#pragma unroll
    for (int c = 0; c < 2; c++) {
      int col = wv * 32 + c * 16 + col16;
      float bj = m.bias ? m.bias[col] : 0.f;
#pragma unroll
      for (int g = 0; g < 4; g++)
        sA[(rt * 16 + quad * 4 + g) * ESTRIDE + col] = f2bf(acc[rt * 2 + c][g] + bj);
    }
  __syncthreads();
  {
    int rr = tid / TPR, d = tid % TPR;
    int rowg = r0 + rr;
    if (rowg < NN) {
      const u16* sp2 = sA + rr * ESTRIDE + d * 64;
      uint4* o = (uint4*)(m.out + (long)rowg * 128 + d * 64);
#pragma unroll
      for (int e = 0; e < 8; e++) {
        const uint2* s2 = (const uint2*)(sp2 + e * 8);
        uint2 lo = s2[0], hi = s2[1];
        o[e] = make_uint4(lo.x, lo.y, hi.x, hi.y);
      }
    }
  }
  if (m.part) {
    __shared__ float ps[256], pq[256];
    int col = tid & 127, hf = tid >> 7;
    float s = 0.f, q = 0.f;
#pragma unroll
    for (int r = 0; r < 64; r++) {
      int rr = hf * 64 + r;
      if (r0 + rr < NN) {
        float v = bf2f(sA[rr * ESTRIDE + col]);
        s += v;
        q += v * v;
      }
    }
    ps[tid] = s;
    pq[tid] = q;
    __syncthreads();
    if (tid < 128) {
      m.part[(long)blockIdx.x * 256 + tid] = ps[tid] + ps[tid + 128];
      m.part[(long)blockIdx.x * 256 + 128 + tid] = pq[tid] + pq[tid + 128];
    }
  }
}

// ------------- fused: S-gather + ET GEMM + mean + preprocess GEMM -------------
__global__ __launch_bounds__(256) void k_etpre(const u16* __restrict__ Xg,
                                               const u16* __restrict__ asum,
                                               const u16* __restrict__ Wet,
                                               const u16* __restrict__ Wpre,
                                               const float* __restrict__ b_int,
                                               const float* __restrict__ b_pre,
                                               const int* __restrict__ off,
                                               const int2* __restrict__ cpk,
                                               u16* __restrict__ out, float* part) {
  __shared__ __align__(16) u16 sA[64 * ASTRIDE];
  __shared__ __align__(16) u16 sE[64 * 32];
  int tid = threadIdx.x;
  int wv = tid >> 6, lane = tid & 63;
  int col16 = lane & 15, quad = lane >> 4;
  int r0 = blockIdx.x * 64;

  // gather S = segsum(Xg) into sA FIRST (no live accumulators during gather)
  gather_lds<0>(sA, Xg, off, cpk, nullptr, r0);
  // stage asum [64 x 16] into sE cols 0..15, zero 16..31
  {
    int row = tid >> 2, seg = tid & 3;
    int ra = r0 + row;
    if (ra >= NN) ra = NN - 1;
    if (seg < 2)
      *(uint4*)(sE + row * 32 + seg * 8) = *(const uint4*)(asum + (long)ra * 16 + seg * 8);
    else
      *(uint4*)(sE + row * 32 + seg * 8) = make_uint4(0, 0, 0, 0);
  }
  bfrag be[2];
#pragma unroll
  for (int c = 0; c < 2; c++)
    be[c] = *(const bfrag*)(Wet + (long)(wv * 32 + c * 16 + col16) * 32 + quad * 8);
  __syncthreads();
  ffrag accE[8];
#pragma unroll
  for (int i = 0; i < 8; i++)
#pragma unroll
    for (int g = 0; g < 4; g++) accE[i][g] = 0.f;
#pragma unroll
  for (int rt = 0; rt < 4; rt++) {
    bfrag af = *(const bfrag*)(sE + (rt * 16 + col16) * 32 + quad * 8);
    accE[rt * 2 + 0] = __builtin_amdgcn_mfma_f32_16x16x32_bf16(af, be[0], accE[rt * 2 + 0], 0, 0, 0);
    accE[rt * 2 + 1] = __builtin_amdgcn_mfma_f32_16x16x32_bf16(af, be[1], accE[rt * 2 + 1], 0, 0, 0);
  }
  // h = (accE + S + cnt*b)/max(cnt,1) in-place; cnt[r] = off[r+1]-off[r]
#pragma unroll
  for (int rt = 0; rt < 4; rt++)
#pragma unroll
    for (int g = 0; g < 4; g++) {
      int rr = rt * 16 + quad * 4 + g;
      int r = r0 + rr;
      int cc = (r < NN) ? off[r + 1] - off[r] : 0;
      float inv = 1.f / (float)(cc > 1 ? cc : 1);
#pragma unroll
      for (int c = 0; c < 2; c++) {
        int col = wv * 32 + c * 16 + col16;
        float bj = b_int[col];
        float v = accE[rt * 2 + c][g] + bf2f(sA[rr * ASTRIDE + col]);
        v = (v + (float)cc * bj) * inv;
        sA[rr * ASTRIDE + col] = f2bf(v);
      }
    }
  bfrag b1[2][4];
#pragma unroll
  for (int c = 0; c < 2; c++)
#pragma unroll
    for (int kb = 0; kb < 4; kb++)
      b1[c][kb] = *(const bfrag*)(Wpre + (long)(wv * 32 + c * 16 + col16) * 128 + kb * 32 + quad * 8);
  __syncthreads();
  ffrag a2[8];
#pragma unroll
  for (int i = 0; i < 8; i++)
#pragma unroll
    for (int g = 0; g < 4; g++) a2[i][g] = 0.f;
#pragma unroll
  for (int kb = 0; kb < 4; kb++)
#pragma unroll
    for (int rt = 0; rt < 4; rt++) {
      bfrag af = *(const bfrag*)(sA + (rt * 16 + col16) * ASTRIDE + kb * 32 + quad * 8);
      a2[rt * 2 + 0] = __builtin_amdgcn_mfma_f32_16x16x32_bf16(af, b1[0][kb], a2[rt * 2 + 0], 0, 0, 0);
      a2[rt * 2 + 1] = __builtin_amdgcn_mfma_f32_16x16x32_bf16(af, b1[1][kb], a2[rt * 2 + 1], 0, 0, 0);
    }
  __syncthreads();
#pragma unroll
  for (int rt = 0; rt < 4; rt++)
#pragma unroll
    for (int c = 0; c < 2; c++) {
      int col = wv * 32 + c * 16 + col16;
      float bj = b_pre[col];
#pragma unroll
      for (int g = 0; g < 4; g++)
        sA[(rt * 16 + quad * 4 + g) * ESTRIDE + col] = f2bf(a2[rt * 2 + c][g] + bj);
    }
  __syncthreads();
  {
    int rr = tid >> 2, d = tid & 3;
    int rowg = r0 + rr;
    if (rowg < NN) {
      const u16* sp2 = sA + rr * ESTRIDE + d * 32;
      uint4* o = (uint4*)(out + (long)rowg * 128 + d * 32);
#pragma unroll
      for (int e = 0; e < 4; e++) {
        const uint2* s2 = (const uint2*)(sp2 + e * 8);
        uint2 lo = s2[0], hi = s2[1];
        o[e] = make_uint4(lo.x, lo.y, hi.x, hi.y);
      }
    }
  }
  {
    __shared__ float ps[256], pq[256];
    int col = tid & 127, hf = tid >> 7;
    float s = 0.f, q = 0.f;
#pragma unroll
    for (int r = 0; r < 32; r++) {
      int rr = hf * 32 + r;
      if (r0 + rr < NN) {
        float v = bf2f(sA[rr * ESTRIDE + col]);
        s += v;
        q += v * v;
      }
    }
    ps[tid] = s;
    pq[tid] = q;
    __syncthreads();
    if (tid < 128) {
      part[(long)blockIdx.x * 256 + tid] = ps[tid] + ps[tid + 128];
      part[(long)blockIdx.x * 256 + 128 + tid] = pq[tid] + pq[tid + 128];
    }
  }
}

// ------------- fused cheb layer: out = relu(BN?(hb)@WD + T1@W1 + L(T1)@V2 + b) -------------
template <int BN>
__global__ __launch_bounds__(256) void k_cheb(const u16* __restrict__ hb,
                                              const u16* __restrict__ T1,
                                              const int* __restrict__ off,
                                              const int2* __restrict__ cpk,
                                              const float* __restrict__ cnorm,
                                              const u16* __restrict__ WD,
                                              const u16* __restrict__ W1,
                                              const u16* __restrict__ V2,
                                              const float* __restrict__ bias,
                                              const float* __restrict__ ab,
                                              u16* __restrict__ out) {
  __shared__ __align__(16) u16 sA[64 * ASTRIDE];
  int tid = threadIdx.x;
  int wv = tid >> 6, lane = tid & 63;
  int col16 = lane & 15, quad = lane >> 4;
  int r0 = blockIdx.x * 64;

  // phase 1: gather L(T1) -> sA ; MFMA with V2 (acc init deferred past gather)
  gather_lds<1>(sA, T1, off, cpk, cnorm, r0);
  bfrag bv[2][4];
#pragma unroll
  for (int c = 0; c < 2; c++)
#pragma unroll
    for (int kb = 0; kb < 4; kb++)
      bv[c][kb] = *(const bfrag*)(V2 + (long)(wv * 32 + c * 16 + col16) * 128 + kb * 32 + quad * 8);
  __syncthreads();
  ffrag acc[8];
#pragma unroll
  for (int i = 0; i < 8; i++)
#pragma unroll
    for (int g = 0; g < 4; g++) acc[i][g] = 0.f;
#pragma unroll
  for (int kb = 0; kb < 4; kb++)
#pragma unroll
    for (int rt = 0; rt < 4; rt++) {
      bfrag af = *(const bfrag*)(sA + (rt * 16 + col16) * ASTRIDE + kb * 32 + quad * 8);
      acc[rt * 2 + 0] = __builtin_amdgcn_mfma_f32_16x16x32_bf16(af, bv[0][kb], acc[rt * 2 + 0], 0, 0, 0);
      acc[rt * 2 + 1] = __builtin_amdgcn_mfma_f32_16x16x32_bf16(af, bv[1][kb], acc[rt * 2 + 1], 0, 0, 0);
    }
  __syncthreads();

  // phase 2: stage hb own rows (BN+ReLU fused when BN=1) ; MFMA with WD
  {
    int row = tid >> 2, seg = tid & 3;
    int ra = r0 + row;
    if (ra >= NN) ra = NN - 1;
    const u16* gs = hb + (long)ra * 128 + seg * 32;
    uint4* lp = (uint4*)(sA + row * ASTRIDE + seg * 32);
    if (BN) {
#pragma unroll
      for (int e = 0; e < 4; e++) {
        uint4 v = *(const uint4*)(gs + e * 8);
        int cb = seg * 32 + e * 8;
        float f0 = fmaxf(fmaf(ab[cb + 0], __uint_as_float(v.x << 16), ab[128 + cb + 0]), 0.f);
        float f1 = fmaxf(fmaf(ab[cb + 1], __uint_as_float(v.x & 0xffff0000u), ab[128 + cb + 1]), 0.f);
        float f2 = fmaxf(fmaf(ab[cb + 2], __uint_as_float(v.y << 16), ab[128 + cb + 2]), 0.f);
        float f3 = fmaxf(fmaf(ab[cb + 3], __uint_as_float(v.y & 0xffff0000u), ab[128 + cb + 3]), 0.f);
        float f4 = fmaxf(fmaf(ab[cb + 4], __uint_as_float(v.z << 16), ab[128 + cb + 4]), 0.f);
        float f5 = fmaxf(fmaf(ab[cb + 5], __uint_as_float(v.z & 0xffff0000u), ab[128 + cb + 5]), 0.f);
        float f6 = fmaxf(fmaf(ab[cb + 6], __uint_as_float(v.w << 16), ab[128 + cb + 6]), 0.f);
        float f7 = fmaxf(fmaf(ab[cb + 7], __uint_as_float(v.w & 0xffff0000u), ab[128 + cb + 7]), 0.f);
        uint4 o;
        o.x = (u32)f2bf(f0) | ((u32)f2bf(f1) << 16);
        o.y = (u32)f2bf(f2) | ((u32)f2bf(f3) << 16);
        o.z = (u32)f2bf(f4) | ((u32)f2bf(f5) << 16);
        o.w = (u32)f2bf(f6) | ((u32)f2bf(f7) << 16);
        lp[e] = o;
      }
    } else {
#pragma unroll
      for (int e = 0; e < 4; e++) lp[e] = *(const uint4*)(gs + e * 8);
    }
  }
#pragma unroll
  for (int c = 0; c < 2; c++)
#pragma unroll
    for (int kb = 0; kb < 4; kb++)
      bv[c][kb] = *(const bfrag*)(WD + (long)(wv * 32 + c * 16 + col16) * 128 + kb * 32 + quad * 8);
  __syncthreads();
#pragma unroll
  for (int kb = 0; kb < 4; kb++)
#pragma unroll
    for (int rt = 0; rt < 4; rt++) {
      bfrag af = *(const bfrag*)(sA + (rt * 16 + col16) * ASTRIDE + kb * 32 + quad * 8);
      acc[rt * 2 + 0] = __builtin_amdgcn_mfma_f32_16x16x32_bf16(af, bv[0][kb], acc[rt * 2 + 0], 0, 0, 0);
      acc[rt * 2 + 1] = __builtin_amdgcn_mfma_f32_16x16x32_bf16(af, bv[1][kb], acc[rt * 2 + 1], 0, 0, 0);
    }
  __syncthreads();

  // phase 3: stage T1 own rows ; MFMA with W1
  {
    int row = tid >> 2, seg = tid & 3;
    int ra = r0 + row;
    if (ra >= NN) ra = NN - 1;
    const u16* gs = T1 + (long)ra * 128 + seg * 32;
    uint4* lp = (uint4*)(sA + row * ASTRIDE + seg * 32);
#pragma unroll
    for (int e = 0; e < 4; e++) lp[e] = *(const uint4*)(gs + e * 8);
  }
#pragma unroll
  for (int c = 0; c < 2; c++)
#pragma unroll
    for (int kb = 0; kb < 4; kb++)
      bv[c][kb] = *(const bfrag*)(W1 + (long)(wv * 32 + c * 16 + col16) * 128 + kb * 32 + quad * 8);
  __syncthreads();
#pragma unroll
  for (int kb = 0; kb < 4; kb++)
#pragma unroll
    for (int rt = 0; rt < 4; rt++) {
      bfrag af = *(const bfrag*)(sA + (rt * 16 + col16) * ASTRIDE + kb * 32 + quad * 8);
      acc[rt * 2 + 0] = __builtin_amdgcn_mfma_f32_16x16x32_bf16(af, bv[0][kb], acc[rt * 2 + 0], 0, 0, 0);
      acc[rt * 2 + 1] = __builtin_amdgcn_mfma_f32_16x16x32_bf16(af, bv[1][kb], acc[rt * 2 + 1], 0, 0, 0);
    }
  __syncthreads();

  // epilogue: +bias, relu, repack, store
#pragma unroll
  for (int rt = 0; rt < 4; rt++)
#pragma unroll
    for (int c = 0; c < 2; c++) {
      int col = wv * 32 + c * 16 + col16;
      float bj = bias[col];
#pragma unroll
      for (int g = 0; g < 4; g++)
        sA[(rt * 16 + quad * 4 + g) * ESTRIDE + col] = f2bf(fmaxf(acc[rt * 2 + c][g] + bj, 0.f));
    }
  __syncthreads();
  {
    int rr = tid >> 2, d = tid & 3;
    int rowg = r0 + rr;
    if (rowg < NN) {
      const u16* sp2 = sA + rr * ESTRIDE + d * 32;
      uint4* o = (uint4*)(out + (long)rowg * 128 + d * 32);
#pragma unroll
      for (int e = 0; e < 4; e++) {
        const uint2* s2 = (const uint2*)(sp2 + e * 8);
        uint2 lo = s2[0], hi = s2[1];
        o[e] = make_uint4(lo.x, lo.y, hi.x, hi.y);
      }
    }
  }
}

// ------------- reduce partials + BN finalize fused -------------
__global__ void k_redfin(const float* __restrict__ part, const float* __restrict__ gamma,
                         const float* __restrict__ beta, float* ab, int nblk) {
  int tid = threadIdx.x;
  int col = blockIdx.x * 16 + (tid & 15);
  int ch = tid >> 4;
  float s = 0.f, q = 0.f;
  for (int b = ch; b < nblk; b += 16) {
    s += part[(long)b * 256 + col];
    q += part[(long)b * 256 + 128 + col];
  }
  __shared__ float sh[256], qh[256];
  sh[tid] = s;
  qh[tid] = q;
  __syncthreads();
  if (tid < 16) {
    float ts = 0.f, tq = 0.f;
#pragma unroll
    for (int i = 0; i < 16; i++) {
      ts += sh[i * 16 + tid];
      tq += qh[i * 16 + tid];
    }
    int j = blockIdx.x * 16 + tid;
    float m = ts * (1.f / (float)NN);
    float v = fmaxf(tq * (1.f / (float)NN) - m * m, 0.f);
    float a = gamma[j] * rsqrtf(v + 1e-5f);
    ab[j] = a;
    ab[128 + j] = beta[j] - m * a;
  }
}

__global__ void k_out(const u16* __restrict__ z, const float* __restrict__ ab,
                      const float* __restrict__ wout, const float* __restrict__ bout,
                      const u32* __restrict__ gp, void* __restrict__ y) {
  int node = blockIdx.x * 4 + (threadIdx.x >> 6);
  if (node >= NN) return;
  int lane = threadIdx.x & 63;
  float s = 0.f;
#pragma unroll
  for (int c = lane; c < 128; c += 64) {
    float zz = bf2f(z[(long)node * 128 + c]);
    float h = fmaxf(ab[c] * zz + ab[128 + c], 0.f);
    s += h * wout[c];
  }
#pragma unroll
  for (int o = 32; o > 0; o >>= 1) s += __shfl_down(s, o);
  if (lane == 0) {
    float r = s + bout[0];
    if (gp[0] == BF16ONE2) ((u16*)y)[node] = f2bf(r);
    else ((float*)y)[node] = r;
  }
}

extern "C" void kernel_launch(void* const* d_in, const int* in_sizes, int n_in,
                              void* d_out, int out_size, void* d_ws, size_t ws_size,
                              hipStream_t stream) {
  const void* x = d_in[0];
  const int* ei = (const int*)d_in[1];
  const void* eattr = d_in[2];
  const u32* gp = (const u32*)d_in[7];
  (void)in_sizes; (void)n_in; (void)out_size; (void)ws_size;

  char* w = (char*)d_ws;
  size_t p = 0;
  auto alloc = [&](size_t b) { size_t r = p; p += (b + 255) & ~(size_t)255; return r; };
  size_t o_deg = alloc((size_t)NN * 4);
  size_t o_off = alloc((size_t)(NN + 1) * 4);
  size_t o_bcnt = alloc((size_t)NBKT * NBLK * 4);
  size_t o_rbcnt = alloc((size_t)NBKT * NBLK * 4);
  size_t o_btot = alloc((size_t)2 * NBKT * 4);
  size_t o_bbase = alloc((size_t)(NBKT + 1) * 4);
  size_t o_rbbase = alloc((size_t)(NBKT + 1) * 4);
  size_t o_ab = alloc(512 * 4);
  size_t o_wq = alloc((size_t)151552 * 2);
  size_t o_wf = alloc((size_t)1281 * 4);
  size_t o_cpk = alloc((size_t)NE * 8);
  size_t o_cnrm = alloc((size_t)NE * 4);
  size_t o_asum = alloc((size_t)NN * 16 * 2);
  size_t o_part = alloc((size_t)1563 * 256 * 4);
  size_t o_Bx = alloc((size_t)NN * 128 * 2);
  size_t o_Bt = alloc((size_t)NN * 128 * 2);

  int* deg = (int*)(w + o_deg);
  int* off = (int*)(w + o_off);
  int* bcnt = (int*)(w + o_bcnt);
  int* rbcnt = (int*)(w + o_rbcnt);
  int* btot = (int*)(w + o_btot);
  int* bbase = (int*)(w + o_bbase);
  int* rbbase = (int*)(w + o_rbbase);
  float* abA = (float*)(w + o_ab);
  float* abB = abA + 256;
  u16* wq = (u16*)(w + o_wq);
  float* wf = (float*)(w + o_wf);
  int2* cpk = (int2*)(w + o_cpk);
  float* cnrm = (float*)(w + o_cnrm);
  u16* asum = (u16*)(w + o_asum);
  float* part = (float*)(w + o_part);
  u16* Bx = (u16*)(w + o_Bx);
  u16* Bt = (u16*)(w + o_Bt);
  // staging overlays on Bx (10 MB < 25.6 MB; dead before k_mgemm writes Bx)
  u32* sle = (u32*)Bx;
  u32* srow = sle + NE;
  u16* srl = (u16*)(srow + NE);

  int gS = (NN + 7) / 8;
  int gG1 = (NN + 127) / 128;  // 782
  int gG2 = (NN + 63) / 64;    // 1563

  {
    PrepArgs a;
    for (int i = 0; i < 16; i++) a.in[i] = d_in[3 + i];
    k_prep<<<64, 256, 0, stream>>>(a, gp, wq, wf);
  }

  // ---- CSR build: LDS two-level counting sort (no global atomics, no memset)
  k_cnt<<<NBLK, 256, 0, stream>>>(ei, bcnt, rbcnt);
  k_bscan<<<2 * NBKT, 256, 0, stream>>>(bcnt, rbcnt, btot);
  k_bbase<<<1, 256, 0, stream>>>(btot, bbase, rbbase, off);
  k_scat<<<NBLK, 256, 0, stream>>>(ei, bcnt, rbcnt, bbase, rbbase, sle, srow, srl);
  k_fine<<<NBKT, 256, 0, stream>>>(sle, srow, bbase, off, cpk);
  k_deg<<<NBKT, 256, 0, stream>>>(srl, rbbase, deg);

  k_asum<<<(NN * 16 + 255) / 256, 256, 0, stream>>>(eattr, gp, asum, off, cpk, deg, cnrm);

  // ---- Xg = x @ Wx -> Bx
  {
    MArgs a = {};
    a.A0 = x; a.W0T = wq + OWXT; a.a0raw = 1;
    a.out = Bx; a.gp = gp;
    k_mgemm<<<gG1, 256, 0, stream>>>(a);
  }
  // ---- fused: S = segsum(Xg), h = (S+asum@We+cnt*b)/cnt, z = h@Wpre+b -> Bt
  k_etpre<<<gG2, 256, 0, stream>>>(Bx, asum, wq + OWET, wq + OWPRE, wf + 0, wf + 128,
                                   off, cpk, Bt, part);
  k_redfin<<<8, 256, 0, stream>>>(part, wf + 256, wf + 384, abA, gG2);

  // ---- cheb1 (BN fused into consumers; hb never materialized)
  k_spmm<1><<<gS, 256, 0, stream>>>(Bt, Bx, off, cpk, cnrm, abA);
  k_cheb<1><<<gG2, 256, 0, stream>>>(Bt, Bx, off, cpk, cnrm,
                                     wq + OWD1, wq + OW11, wq + OV21, wf + 512, abA, Bt);

  // ---- cheb2 (plain)
  k_spmm<0><<<gS, 256, 0, stream>>>(Bt, Bx, off, cpk, cnrm, nullptr);
  k_cheb<0><<<gG2, 256, 0, stream>>>(Bt, Bx, off, cpk, cnrm,
                                     wq + OWD2, wq + OW12, wq + OV22, wf + 640, nullptr, Bt);

  // ---- postprocess: z2 = h3@Wpost + b -> Bx (+partials) ; BN+relu+dot -> y
  {
    MArgs a = {};
    a.A0 = Bt; a.W0T = wq + OWPOST;
    a.bias = wf + 768; a.out = Bx; a.gp = gp; a.part = part;
    k_mgemm<<<gG1, 256, 0, stream>>>(a);
  }
  k_redfin<<<8, 256, 0, stream>>>(part, wf + 896, wf + 1024, abB, gG1);
  k_out<<<(NN + 3) / 4, 256, 0, stream>>>(Bx, abB, wf + 1152, wf + 1280, gp, d_out);
}